// Round 3
// baseline (679.334 us; speedup 1.0000x reference)
//
#include <hip/hip_runtime.h>
#include <cstdint>
#include <cstddef>

// ---- problem constants ----
#define Hd    3584
#define NHq   28
#define NKVh  4
#define Dh    128
#define GRP   7
#define Bb    4
#define Ss    1024
#define Tt    4096
#define NBLK  512
#define BSZ   16
#define QKVO  4608
#define ATTN_SCALE 0.08838834764831845f  // 1/sqrt(128)

typedef short s8v __attribute__((ext_vector_type(8)));   // 8 x bf16 (4 VGPRs)
typedef float f4v __attribute__((ext_vector_type(4)));   // 4 x f32 accum

__device__ __forceinline__ ushort bf16r(float f) {       // RNE f32->bf16
    uint32_t u = __float_as_uint(f);
    u += 0x7fff + ((u >> 16) & 1);
    return (ushort)(u >> 16);
}

__device__ __forceinline__ uint32_t pkbf(float a, float b) {  // pack 2 bf16 -> b32
    return (uint32_t)bf16r(a) | ((uint32_t)bf16r(b) << 16);
}

__device__ __forceinline__ f4v mfma16(s8v a, s8v b, f4v c) {
    return __builtin_amdgcn_mfma_f32_16x16x32_bf16(a, b, c, 0, 0, 0);
}

// async global->LDS, 16B per lane; LDS dest = wave-uniform base + lane*16
__device__ __forceinline__ void async_cp16(ushort* lds, const ushort* g) {
    __builtin_amdgcn_global_load_lds(
        (const __attribute__((address_space(1))) uint32_t*)(uintptr_t)g,
        (__attribute__((address_space(3))) uint32_t*)(uintptr_t)lds,
        16, 0, 0);
}

// ---------------- fp32 -> bf16 convert (vectorized) ----------------
__global__ __launch_bounds__(256) void cvt_bf16(const float* __restrict__ src,
                                                ushort* __restrict__ dst, int n4) {
    int i = blockIdx.x * 256 + threadIdx.x;
    if (i >= n4) return;
    float4 f = ((const float4*)src)[i];
    ushort4 u;
    u.x = bf16r(f.x); u.y = bf16r(f.y); u.z = bf16r(f.z); u.w = bf16r(f.w);
    ((ushort4*)dst)[i] = u;
}

// ---------------- cache passthrough copy ----------------
__global__ __launch_bounds__(256) void copy_f4(const float* __restrict__ src,
                                               float* __restrict__ dst, int n4) {
    int i = blockIdx.x * 256 + threadIdx.x;
    if (i < n4) ((float4*)dst)[i] = ((const float4*)src)[i];
}

// ======== unified 256x256 / BK=32 / triple-buffer / 1-barrier-per-tile ========
// 8 waves (4M x 2N), per-wave 64x128 output (acc[4][8]).  Per tile per wave:
// {8 ds_read (af,bfr0-3)} | {4 ds_read (bfr4-7) + 4 gload_lds} ->
// lgkmcnt(4) -> 16 MFMA -> lgkmcnt(0) -> 16 MFMA -> vmcnt(4) -> s_barrier.
// Hazard proof: tile t reads buf t%3, stages buf (t+2)%3 == buf (t-1)%3; the
// single end-of-tile barrier bounds wave drift to one tile, and each wave's
// vmcnt(4) before barrier t-1 drains all tile-t staging -> no overlap race.
// sched_barrier(0) directly after every s_barrier: prevents the backend from
// hoisting next-tile ds_reads above the barrier (rule-#18 class hazard; my
// vmcnt only proves MY staging drained, the barrier is what publishes peers').
// Tail: when t+2>=NT nothing is staged and vmcnt(0) drains the remainder.

// ---------------- O-proj GEMM: C[M,N] = A[M,K] @ Bw[N,K]^T ----------------
__global__ __launch_bounds__(512, 2) void gemm_bt(
    const ushort* __restrict__ A, const ushort* __restrict__ Bw,
    float* __restrict__ C, int N, int K)
{
    __shared__ ushort As[3][256 * 32];
    __shared__ ushort Bs[3][256 * 32];
    const int tid  = threadIdx.x;
    const int wv   = tid >> 6;
    const int lane = tid & 63;
    const int quad = lane >> 4;
    const int l16  = lane & 15;
    const int m0 = blockIdx.y * 256;
    const int n0 = blockIdx.x * 256;
    const int wm = (wv >> 1) * 64;
    const int wn = (wv & 1) * 128;

    f4v zero = {0.f, 0.f, 0.f, 0.f};
    f4v acc[4][8];
    #pragma unroll
    for (int i = 0; i < 4; i++)
        #pragma unroll
        for (int j = 0; j < 8; j++) acc[i][j] = zero;

    const int swz = ((lane & 3) ^ ((lane >> 3) & 3)) * 8;
    const int rS  = lane >> 2;
    const ushort* gA = A  + (size_t)(m0 + wv * 32 + rS) * K + swz;
    const ushort* gB = Bw + (size_t)(n0 + wv * 32 + rS) * K + swz;
    const int stA = (wv * 32) * 32;
    const int fsw = ((l16 >> 1) & 3) * 8;

    // prologue: stage tiles 0 and 1 (8 issues/wave), wait for tile 0
    #pragma unroll
    for (int t = 0; t < 2; t++) {
        async_cp16(&As[t][stA],           gA + t * 32);
        async_cp16(&As[t][stA + 16 * 32], gA + (size_t)16 * K + t * 32);
        async_cp16(&Bs[t][stA],           gB + t * 32);
        async_cp16(&Bs[t][stA + 16 * 32], gB + (size_t)16 * K + t * 32);
    }
    asm volatile("s_waitcnt vmcnt(4)" ::: "memory");
    __builtin_amdgcn_s_barrier();
    __builtin_amdgcn_sched_barrier(0);

    const int NT = K / 32;
    for (int t = 0; t < NT; t++) {
        const ushort* Ac = As[t % 3];
        const ushort* Bc = Bs[t % 3];
        ushort* An = (ushort*)As[(t + 2) % 3];
        ushort* Bn = (ushort*)Bs[(t + 2) % 3];
        const int kn = (t + 2) * 32;
        const bool pf = (t + 2 < NT);

        s8v af[4], bfr[8];
        // group 1: 8 ds_reads (af, bfr0-3)
        #pragma unroll
        for (int i = 0; i < 4; i++)
            af[i] = *(const s8v*)&Ac[(wm + i * 16 + l16) * 32 + ((quad * 8) ^ fsw)];
        #pragma unroll
        for (int j = 0; j < 4; j++)
            bfr[j] = *(const s8v*)&Bc[(wn + j * 16 + l16) * 32 + ((quad * 8) ^ fsw)];
        __builtin_amdgcn_sched_barrier(0);      // pin group-1 reads before group 2
        // group 2: 4 ds_reads + 4 staging issues
        #pragma unroll
        for (int j = 4; j < 8; j++)
            bfr[j] = *(const s8v*)&Bc[(wn + j * 16 + l16) * 32 + ((quad * 8) ^ fsw)];
        if (pf) {
            async_cp16(&An[stA],           gA + kn);
            async_cp16(&An[stA + 16 * 32], gA + (size_t)16 * K + kn);
            async_cp16(&Bn[stA],           gB + kn);
            async_cp16(&Bn[stA + 16 * 32], gB + (size_t)16 * K + kn);
        }
        asm volatile("s_waitcnt lgkmcnt(4)" ::: "memory");   // group 1 landed
        __builtin_amdgcn_sched_barrier(0);
        __builtin_amdgcn_s_setprio(1);
        #pragma unroll
        for (int i = 0; i < 4; i++)
            #pragma unroll
            for (int j = 0; j < 4; j++)
                acc[i][j] = mfma16(af[i], bfr[j], acc[i][j]);
        asm volatile("s_waitcnt lgkmcnt(0)" ::: "memory");   // group 2 landed
        __builtin_amdgcn_sched_barrier(0);
        #pragma unroll
        for (int i = 0; i < 4; i++)
            #pragma unroll
            for (int j = 4; j < 8; j++)
                acc[i][j] = mfma16(af[i], bfr[j], acc[i][j]);
        __builtin_amdgcn_s_setprio(0);
        __builtin_amdgcn_sched_barrier(0);
        if (pf) asm volatile("s_waitcnt vmcnt(4)" ::: "memory");
        else    asm volatile("s_waitcnt vmcnt(0)" ::: "memory");
        __builtin_amdgcn_s_barrier();
        __builtin_amdgcn_sched_barrier(0);
    }

    #pragma unroll
    for (int i = 0; i < 4; i++) {
        const int m = m0 + wm + i * 16 + quad * 4;
        #pragma unroll
        for (int j = 0; j < 8; j++) {
            const int n = n0 + wn + j * 16 + l16;
            float* cp = C + (size_t)m * N + n;
            #pragma unroll
            for (int r = 0; r < 4; r++)
                cp[(size_t)r * N] = acc[i][j][r];
        }
    }
}

// ---------------- fused QKV GEMM + bias + RoPE + scatter ----------------
// Same 256x256 inner loop; wave = 64 tokens x 1 full head slot (128 cols),
// head slot s = blockIdx.x*2 + (wv&1).  RoPE partner d^64 = acc[i][j+4],
// same lane.  Grid (QKVO/256=18, Tt/256=16).
__global__ __launch_bounds__(512, 2) void gemm_qkv(
    const ushort* __restrict__ A, const ushort* __restrict__ Bw,
    const float* __restrict__ bias, const int* __restrict__ pos,
    const int* __restrict__ slot_map,
    ushort* __restrict__ Qb, ushort* __restrict__ Kb, ushort* __restrict__ Vt,
    float* __restrict__ cacheOut)
{
    __shared__ ushort As[3][256 * 32];
    __shared__ ushort Bs[3][256 * 32];
    const int tid  = threadIdx.x;
    const int wv   = tid >> 6;
    const int lane = tid & 63;
    const int quad = lane >> 4;
    const int l16  = lane & 15;
    const int m0 = blockIdx.y * 256;
    const int n0 = blockIdx.x * 256;
    const int wm = (wv >> 1) * 64;
    const int wn = (wv & 1) * 128;

    f4v zero = {0.f, 0.f, 0.f, 0.f};
    f4v acc[4][8];
    #pragma unroll
    for (int i = 0; i < 4; i++)
        #pragma unroll
        for (int j = 0; j < 8; j++) acc[i][j] = zero;

    const int swz = ((lane & 3) ^ ((lane >> 3) & 3)) * 8;
    const int rS  = lane >> 2;
    const ushort* gA = A  + (size_t)(m0 + wv * 32 + rS) * Hd + swz;
    const ushort* gB = Bw + (size_t)(n0 + wv * 32 + rS) * Hd + swz;
    const int stA = (wv * 32) * 32;
    const int fsw = ((l16 >> 1) & 3) * 8;

    #pragma unroll
    for (int t = 0; t < 2; t++) {
        async_cp16(&As[t][stA],           gA + t * 32);
        async_cp16(&As[t][stA + 16 * 32], gA + (size_t)16 * Hd + t * 32);
        async_cp16(&Bs[t][stA],           gB + t * 32);
        async_cp16(&Bs[t][stA + 16 * 32], gB + (size_t)16 * Hd + t * 32);
    }
    asm volatile("s_waitcnt vmcnt(4)" ::: "memory");
    __builtin_amdgcn_s_barrier();
    __builtin_amdgcn_sched_barrier(0);

    const int NT = Hd / 32;            // 112
    for (int t = 0; t < NT; t++) {
        const ushort* Ac = As[t % 3];
        const ushort* Bc = Bs[t % 3];
        ushort* An = (ushort*)As[(t + 2) % 3];
        ushort* Bn = (ushort*)Bs[(t + 2) % 3];
        const int kn = (t + 2) * 32;
        const bool pf = (t + 2 < NT);

        s8v af[4], bfr[8];
        #pragma unroll
        for (int i = 0; i < 4; i++)
            af[i] = *(const s8v*)&Ac[(wm + i * 16 + l16) * 32 + ((quad * 8) ^ fsw)];
        #pragma unroll
        for (int j = 0; j < 4; j++)
            bfr[j] = *(const s8v*)&Bc[(wn + j * 16 + l16) * 32 + ((quad * 8) ^ fsw)];
        __builtin_amdgcn_sched_barrier(0);
        #pragma unroll
        for (int j = 4; j < 8; j++)
            bfr[j] = *(const s8v*)&Bc[(wn + j * 16 + l16) * 32 + ((quad * 8) ^ fsw)];
        if (pf) {
            async_cp16(&An[stA],           gA + kn);
            async_cp16(&An[stA + 16 * 32], gA + (size_t)16 * Hd + kn);
            async_cp16(&Bn[stA],           gB + kn);
            async_cp16(&Bn[stA + 16 * 32], gB + (size_t)16 * Hd + kn);
        }
        asm volatile("s_waitcnt lgkmcnt(4)" ::: "memory");
        __builtin_amdgcn_sched_barrier(0);
        __builtin_amdgcn_s_setprio(1);
        #pragma unroll
        for (int i = 0; i < 4; i++)
            #pragma unroll
            for (int j = 0; j < 4; j++)
                acc[i][j] = mfma16(af[i], bfr[j], acc[i][j]);
        asm volatile("s_waitcnt lgkmcnt(0)" ::: "memory");
        __builtin_amdgcn_sched_barrier(0);
        #pragma unroll
        for (int i = 0; i < 4; i++)
            #pragma unroll
            for (int j = 4; j < 8; j++)
                acc[i][j] = mfma16(af[i], bfr[j], acc[i][j]);
        __builtin_amdgcn_s_setprio(0);
        __builtin_amdgcn_sched_barrier(0);
        if (pf) asm volatile("s_waitcnt vmcnt(4)" ::: "memory");
        else    asm volatile("s_waitcnt vmcnt(0)" ::: "memory");
        __builtin_amdgcn_s_barrier();
        __builtin_amdgcn_sched_barrier(0);
    }

    // ---- fused epilogue: this wave owns head slot s, tokens m0+wm..+63 ----
    const int s = blockIdx.x * 2 + (wv & 1);
    float bv[8];
    #pragma unroll
    for (int j = 0; j < 8; j++) bv[j] = bias[s * 128 + j * 16 + l16];

    if (s < NHq + NKVh) {              // Q or K: RoPE
        float invf[4];
        #pragma unroll
        for (int j = 0; j < 4; j++)
            invf[j] = __expf(-0.14391156831212787f * (float)(j * 16 + l16));
        #pragma unroll
        for (int i = 0; i < 4; i++) {
            #pragma unroll
            for (int r = 0; r < 4; r++) {
                const int t = m0 + wm + i * 16 + quad * 4 + r;
                const float p = (float)pos[t];
                float od[8];
                #pragma unroll
                for (int j = 0; j < 4; j++) {
                    float sv, cv;
                    __sincosf(p * invf[j], &sv, &cv);
                    const float x1 = acc[i][j][r] + bv[j];
                    const float x2 = acc[i][j + 4][r] + bv[j + 4];
                    od[j]     = x1 * cv - x2 * sv;
                    od[j + 4] = x2 * cv + x1 * sv;
                }
                if (s < NHq) {
                    #pragma unroll
                    for (int j = 0; j < 8; j++)
                        Qb[((size_t)t * NHq + s) * Dh + j * 16 + l16] = bf16r(od[j]);
                } else {
                    const int kvh = s - NHq;
                    const int slot = slot_map[t];
                    #pragma unroll
                    for (int j = 0; j < 8; j++) {
                        const int d = j * 16 + l16;
                        Kb[((size_t)t * NKVh + kvh) * Dh + d] = bf16r(od[j]);
                        cacheOut[(size_t)slot * (NKVh * Dh) + kvh * Dh + d] = od[j];
                    }
                }
            }
        }
    } else {                           // V: no RoPE; emit V^T + cache
        const int kvh = s - NHq - NKVh;
        #pragma unroll
        for (int i = 0; i < 4; i++) {
            #pragma unroll
            for (int r = 0; r < 4; r++) {
                const int t = m0 + wm + i * 16 + quad * 4 + r;
                const int slot = slot_map[t];
                const int b = t >> 10, stok = t & 1023;
                #pragma unroll
                for (int j = 0; j < 8; j++) {
                    const float x = acc[i][j][r] + bv[j];
                    const int d = j * 16 + l16;
                    Vt[((size_t)(b * NKVh + kvh) * Dh + d) * Ss + stok] = bf16r(x);
                    cacheOut[(size_t)NBLK * BSZ * NKVh * Dh +
                             (size_t)slot * (NKVh * Dh) + kvh * Dh + d] = x;
                }
            }
        }
    }
}

// ---------------- flash attention, S^T formulation ----------------
__global__ __launch_bounds__(256, 2) void attn(
    const ushort* __restrict__ Qb, const ushort* __restrict__ Kb,
    const ushort* __restrict__ Vt, ushort* __restrict__ ctx)
{
    __shared__ ushort Ksm[128 * 128];
    __shared__ ushort Vsm[128 * 128];

    const int tid  = threadIdx.x;
    const int w    = tid >> 6;
    const int lane = tid & 63;
    const int quad = lane >> 4;
    const int l16  = lane & 15;
    const int qt = (Ss / 128 - 1) - blockIdx.x;   // heavy blocks first
    const int h  = blockIdx.y;
    const int b  = blockIdx.z;
    const int kv = h / GRP;
    const int t0 = b * Ss + qt * 128;

    s8v qf[2][4];
    #pragma unroll
    for (int nt = 0; nt < 2; nt++)
        #pragma unroll
        for (int kd = 0; kd < 4; kd++)
            qf[nt][kd] = *(const s8v*)&Qb[((size_t)(t0 + w * 32 + nt * 16 + l16) * NHq + h) * Dh
                                          + kd * 32 + quad * 8];

    f4v zero = {0.f, 0.f, 0.f, 0.f};
    f4v o[2][8];
    #pragma unroll
    for (int nt = 0; nt < 2; nt++)
        #pragma unroll
        for (int dt = 0; dt < 8; dt++) o[nt][dt] = zero;
    float mstat[2] = {-1e30f, -1e30f};
    float dstat[2] = {0.f, 0.f};

    const int srow = lane >> 4;
    const int gch  = (lane & 15) ^ (w * 4 + srow);
    const ushort* gK = Kb + (size_t)(b * Ss) * (NKVh * Dh) + kv * Dh + gch * 8;
    const ushort* gV = Vt + (size_t)(b * NKVh + kv) * Dh * Ss + gch * 8;

    const int srcq0 = ((quad & 1) << 1) | (quad >> 1);
    const int addr0 = (srcq0 * 16 + l16) * 4;
    const int addr1 = ((srcq0 ^ 1) * 16 + l16) * 4;
    const bool oddq = (quad & 1);
    const bool lowq = (quad < 2);

    for (int kt = 0; kt <= qt; kt++) {
        const bool diag = (kt == qt);

        #pragma unroll
        for (int j = 0; j < 8; j++) {
            const int row = j * 16 + w * 4 + srow;
            async_cp16(&Ksm[(j * 16 + w * 4) * 128],
                       gK + (size_t)(kt * 128 + row) * (NKVh * Dh));
            async_cp16(&Vsm[(j * 16 + w * 4) * 128],
                       gV + (size_t)row * Ss + kt * 128);
        }
        __syncthreads();

        const int smax = diag ? (2 * w + 1) : 7;
        f4v sc[8][2];
        #pragma unroll
        for (int st = 0; st < 8; st++) { sc[st][0] = zero; sc[st][1] = zero; }
        #pragma unroll
        for (int st = 0; st < 8; st++) {
            if (st > smax) continue;
            #pragma unroll
            for (int kd = 0; kd < 4; kd++) {
                s8v kf = *(const s8v*)&Ksm[((st * 16 + l16) * 16 + ((kd * 4 + quad) ^ l16)) * 8];
                sc[st][0] = mfma16(kf, qf[0][kd], sc[st][0]);
                sc[st][1] = mfma16(kf, qf[1][kd], sc[st][1]);
            }
        }

        float alpha[2];
        #pragma unroll
        for (int nt = 0; nt < 2; nt++) {
            const int qcol = w * 32 + nt * 16 + l16;
            float rowm = -1e30f;
            #pragma unroll
            for (int st = 0; st < 8; st++) {
                if (st > smax) continue;
                #pragma unroll
                for (int r = 0; r < 4; r++) {
                    float v = sc[st][nt][r] * ATTN_SCALE;
                    if (diag && (st * 16 + quad * 4 + r > qcol)) v = -1e30f;
                    sc[st][nt][r] = v;
                    rowm = fmaxf(rowm, v);
                }
            }
            rowm = fmaxf(rowm, __shfl_xor(rowm, 16, 64));
            rowm = fmaxf(rowm, __shfl_xor(rowm, 32, 64));
            const float mn = fmaxf(mstat[nt], rowm);
            const float al = __expf(mstat[nt] - mn);
            float rs = 0.f;
            #pragma unroll
            for (int st = 0; st < 8; st++) {
                if (st > smax) continue;
                #pragma unroll
                for (int r = 0; r < 4; r++) {
                    const float p = __expf(sc[st][nt][r] - mn);
                    sc[st][nt][r] = p;
                    rs += p;
                }
            }
            rs += __shfl_xor(rs, 16, 64);
            rs += __shfl_xor(rs, 32, 64);
            dstat[nt] = dstat[nt] * al + rs;
            mstat[nt] = mn;
            alpha[nt] = al;
            #pragma unroll
            for (int dt = 0; dt < 8; dt++)
                #pragma unroll
                for (int r = 0; r < 4; r++) o[nt][dt][r] *= al;
        }

        const int spmax = diag ? w : 3;
        #pragma unroll
        for (int sp = 0; sp < 4; sp++) {
            if (sp > spmax) continue;
            s8v pf[2];
            #pragma unroll
            for (int nt = 0; nt < 2; nt++) {
                const uint32_t a01 = pkbf(sc[2 * sp][nt][0],     sc[2 * sp][nt][1]);
                const uint32_t a23 = pkbf(sc[2 * sp][nt][2],     sc[2 * sp][nt][3]);
                const uint32_t b01 = pkbf(sc[2 * sp + 1][nt][0], sc[2 * sp + 1][nt][1]);
                const uint32_t b23 = pkbf(sc[2 * sp + 1][nt][2], sc[2 * sp + 1][nt][3]);
                const int r0 = __builtin_amdgcn_ds_bpermute(addr0, (int)(oddq ? b01 : a01));
                const int r1 = __builtin_amdgcn_ds_bpermute(addr1, (int)(oddq ? a01 : b01));
                const int r2 = __builtin_amdgcn_ds_bpermute(addr0, (int)(oddq ? b23 : a23));
                const int r3 = __builtin_amdgcn_ds_bpermute(addr1, (int)(oddq ? a23 : b23));
                union { int d[4]; s8v v; } u;
                u.d[0] = lowq ? r0 : r1;
                u.d[1] = lowq ? r2 : r3;
                u.d[2] = lowq ? r1 : r0;
                u.d[3] = lowq ? r3 : r2;
                pf[nt] = u.v;
            }
            #pragma unroll
            for (int dt = 0; dt < 8; dt++) {
                s8v vf = *(const s8v*)&Vsm[((dt * 16 + l16) * 16 + ((sp * 4 + quad) ^ l16)) * 8];
                o[0][dt] = mfma16(vf, pf[0], o[0][dt]);
                o[1][dt] = mfma16(vf, pf[1], o[1][dt]);
            }
        }
        __syncthreads();
    }

    #pragma unroll
    for (int nt = 0; nt < 2; nt++) {
        const float inv = 1.0f / dstat[nt];
        const int trow = t0 + w * 32 + nt * 16 + l16;
        #pragma unroll
        for (int dt = 0; dt < 8; dt++) {
            ushort4 u;
            u.x = bf16r(o[nt][dt][0] * inv);
            u.y = bf16r(o[nt][dt][1] * inv);
            u.z = bf16r(o[nt][dt][2] * inv);
            u.w = bf16r(o[nt][dt][3] * inv);
            *(ushort4*)&ctx[(size_t)trow * Hd + h * Dh + dt * 16 + quad * 4] = u;
        }
    }
}

// ---------------- launch ----------------
extern "C" void kernel_launch(void* const* d_in, const int* in_sizes, int n_in,
                              void* d_out, int out_size, void* d_ws, size_t ws_size,
                              hipStream_t stream)
{
    const int*   positions = (const int*)d_in[0];
    const float* hidden    = (const float*)d_in[1];
    const float* kvc       = (const float*)d_in[2];
    const int*   slot_map  = (const int*)d_in[4];
    const float* w_qkv     = (const float*)d_in[7];
    const float* b_qkv     = (const float*)d_in[8];
    const float* w_o       = (const float*)d_in[9];

    float* out      = (float*)d_out;                 // (T, H) fp32
    float* cacheOut = out + (size_t)Tt * Hd;         // (2,NB,BS,NKV,D) fp32

    char* ws = (char*)d_ws;
    ushort* Xb    = (ushort*)(ws);                   // T*H bf16         29360128
    ushort* Wqkvb = (ushort*)(ws + 29360128);        // 4608*3584 bf16   33030144
    ushort* Wob   = (ushort*)(ws + 62390272);        // 3584*3584 bf16   25690112
    ushort* Qb    = (ushort*)(ws + 88080384);        // T*NH*D bf16      29360128
    ushort* Kb    = (ushort*)(ws + 117440512);       // T*NKV*D bf16      4194304
    ushort* Vt    = (ushort*)(ws + 121634816);       // B*NKV*D*S bf16    4194304
    ushort* ctx   = Xb;                              // alias: Xb dead after gemm_qkv

    cvt_bf16<<<dim3(14336), 256, 0, stream>>>(hidden, Xb, 3670016);
    cvt_bf16<<<dim3(16128), 256, 0, stream>>>(w_qkv, Wqkvb, 4128768);
    cvt_bf16<<<dim3(12544), 256, 0, stream>>>(w_o, Wob, 3211264);
    copy_f4<<<dim3(8192), 256, 0, stream>>>(kvc, cacheOut, 2097152);
    gemm_qkv<<<dim3(QKVO / 256, Tt / 256), 512, 0, stream>>>(
        Xb, Wqkvb, b_qkv, positions, slot_map, Qb, Kb, Vt, cacheOut);
    attn<<<dim3(Ss / 128, NHq, Bb), 256, 0, stream>>>(Qb, Kb, Vt, ctx);
    gemm_bt<<<dim3(Hd / 256, Tt / 256), 512, 0, stream>>>(
        ctx, Wob, out, Hd, Hd);
}

// Round 4
// 641.175 us; speedup vs baseline: 1.0595x; 1.0595x over previous
//
#include <hip/hip_runtime.h>
#include <cstdint>
#include <cstddef>

// ---- problem constants ----
#define Hd    3584
#define NHq   28
#define NKVh  4
#define Dh    128
#define GRP   7
#define Bb    4
#define Ss    1024
#define Tt    4096
#define NBLK  512
#define BSZ   16
#define QKVO  4608
#define ATTN_SCALE 0.08838834764831845f  // 1/sqrt(128)

typedef short s8v __attribute__((ext_vector_type(8)));   // 8 x bf16 (4 VGPRs)
typedef float f4v __attribute__((ext_vector_type(4)));   // 4 x f32 accum

__device__ __forceinline__ ushort bf16r(float f) {       // RNE f32->bf16
    uint32_t u = __float_as_uint(f);
    u += 0x7fff + ((u >> 16) & 1);
    return (ushort)(u >> 16);
}

__device__ __forceinline__ float bf2f(ushort u) {
    uint32_t x = ((uint32_t)u) << 16;
    return __uint_as_float(x);
}

__device__ __forceinline__ uint32_t pkbf(float a, float b) {  // pack 2 bf16 -> b32
    return (uint32_t)bf16r(a) | ((uint32_t)bf16r(b) << 16);
}

__device__ __forceinline__ f4v mfma16(s8v a, s8v b, f4v c) {
    return __builtin_amdgcn_mfma_f32_16x16x32_bf16(a, b, c, 0, 0, 0);
}

// async global->LDS, 16B per lane; LDS dest = wave-uniform base + lane*16
__device__ __forceinline__ void async_cp16(ushort* lds, const ushort* g) {
    __builtin_amdgcn_global_load_lds(
        (const __attribute__((address_space(1))) uint32_t*)(uintptr_t)g,
        (__attribute__((address_space(3))) uint32_t*)(uintptr_t)lds,
        16, 0, 0);
}

// ---------------- fp32 -> bf16 convert (vectorized) ----------------
__global__ __launch_bounds__(256) void cvt_bf16(const float* __restrict__ src,
                                                ushort* __restrict__ dst, int n4) {
    int i = blockIdx.x * 256 + threadIdx.x;
    if (i >= n4) return;
    float4 f = ((const float4*)src)[i];
    ushort4 u;
    u.x = bf16r(f.x); u.y = bf16r(f.y); u.z = bf16r(f.z); u.w = bf16r(f.w);
    ((ushort4*)dst)[i] = u;
}

// ---------------- cache passthrough copy ----------------
__global__ __launch_bounds__(256) void copy_f4(const float* __restrict__ src,
                                               float* __restrict__ dst, int n4) {
    int i = blockIdx.x * 256 + threadIdx.x;
    if (i < n4) ((float4*)dst)[i] = ((const float4*)src)[i];
}

// ======================= GEMM design (R4) =======================
// Evidence (R0/R1/R3): MfmaUtil pinned at 24-28% independent of barrier
// structure => LDS read-BW bound (640 B of ds_read per MFMA caps at ~27%).
// Fix 1: per-wave 64x144 / 64x112 tiles -> 370-400 B/MFMA (cap ~40-48%).
// Fix 2: grids of EXACTLY 512 blocks (2 blocks/CU) -> no 1.125x tail that
// every power-of-2 tiling of N=4608 suffers (factor 9).
// Inner loop: R0-proven single-LDS-buffer, 2 syncthreads per BK=32 tile;
// co-resident block hides the barrier drain (measured: pipelining neutral).
// Source-chunk swizzle c^((row>>1)&3) kept (0 bank conflicts measured).

// ---------------- QKV GEMM + bias: raw[M,4608] = X[M,K] @ Wqkv^T + b ------
// Tile 128x288, 4 waves (2M x 2N), wave 64x144, acc[4][9] (AGPR).
// Grid (4608/288=16, 4096/128=32) = 512 blocks exactly.
__global__ __launch_bounds__(256, 2) void gemm_qkv(
    const ushort* __restrict__ A, const ushort* __restrict__ Bw,
    const float* __restrict__ bias, ushort* __restrict__ raw)
{
    __shared__ ushort Asm_[128 * 32];
    __shared__ ushort Bsm_[288 * 32];
    const int tid  = threadIdx.x;
    const int wv   = tid >> 6;
    const int lane = tid & 63;
    const int quad = lane >> 4;
    const int l16  = lane & 15;
    const int m0 = blockIdx.y * 128;
    const int n0 = blockIdx.x * 288;
    const int wm = (wv >> 1) * 64;
    const int wn = (wv & 1) * 144;

    f4v zero = {0.f, 0.f, 0.f, 0.f};
    f4v acc[4][9];
    #pragma unroll
    for (int i = 0; i < 4; i++)
        #pragma unroll
        for (int j = 0; j < 9; j++) acc[i][j] = zero;

    const int swz = ((lane & 3) ^ ((lane >> 3) & 3)) * 8;   // source chunk xor
    const int rS  = lane >> 2;                              // row in 16-row slot
    const ushort* gA = A  + (size_t)(m0 + rS) * Hd + swz;
    const ushort* gB = Bw + (size_t)(n0 + rS) * Hd + swz;
    const int fsw = ((l16 >> 1) & 3) * 8;                   // fragment chunk xor

    for (int kt = 0; kt < Hd; kt += 32) {
        // stage A: 8 slots of 16 rows; wave w takes slots w, w+4
        #pragma unroll
        for (int i = 0; i < 2; i++) {
            const int sl = wv + 4 * i;
            async_cp16(&Asm_[sl * 16 * 32], gA + (size_t)(sl * 16) * Hd + kt);
        }
        // stage B: 18 slots; wave w takes w+4i, i<5, guard slot<18 (uniform)
        #pragma unroll
        for (int i = 0; i < 5; i++) {
            const int sl = wv + 4 * i;
            if (sl < 18)
                async_cp16(&Bsm_[sl * 16 * 32], gB + (size_t)(sl * 16) * Hd + kt);
        }
        __syncthreads();
        s8v af[4], bfr[9];
        #pragma unroll
        for (int i = 0; i < 4; i++)
            af[i] = *(const s8v*)&Asm_[(wm + i * 16 + l16) * 32 + ((quad * 8) ^ fsw)];
        #pragma unroll
        for (int j = 0; j < 9; j++)
            bfr[j] = *(const s8v*)&Bsm_[(wn + j * 16 + l16) * 32 + ((quad * 8) ^ fsw)];
        #pragma unroll
        for (int i = 0; i < 4; i++)
            #pragma unroll
            for (int j = 0; j < 9; j++)
                acc[i][j] = mfma16(af[i], bfr[j], acc[i][j]);
        __syncthreads();
    }

    // epilogue: + bias, write bf16 raw
    float bv[9];
    #pragma unroll
    for (int j = 0; j < 9; j++) bv[j] = bias[n0 + wn + j * 16 + l16];
    #pragma unroll
    for (int i = 0; i < 4; i++) {
        const int m = m0 + wm + i * 16 + quad * 4;
        #pragma unroll
        for (int j = 0; j < 9; j++) {
            const int n = n0 + wn + j * 16 + l16;
            #pragma unroll
            for (int r = 0; r < 4; r++)
                raw[(size_t)(m + r) * QKVO + n] = bf16r(acc[i][j][r] + bv[j]);
        }
    }
}

// ---------------- RoPE + scatter pass (memory-bound, ~110 MB) ----------------
// wave = one (token, head-slot); lane d<64 handles the (d, d+64) RoPE pair.
__global__ __launch_bounds__(256) void rope_scatter(
    const ushort* __restrict__ raw, const int* __restrict__ pos,
    const int* __restrict__ slot_map,
    ushort* __restrict__ Qb, ushort* __restrict__ Kb, ushort* __restrict__ Vt,
    float* __restrict__ cacheOut)
{
    const int wv   = threadIdx.x >> 6;
    const int d    = threadIdx.x & 63;
    const int job  = blockIdx.x * 4 + wv;          // t*36 + s
    const int t    = job / 36;
    const int s    = job - t * 36;

    const float x1 = bf2f(raw[(size_t)t * QKVO + s * 128 + d]);
    const float x2 = bf2f(raw[(size_t)t * QKVO + s * 128 + d + 64]);

    if (s < NHq + NKVh) {                          // Q or K: RoPE
        const float p = (float)pos[t];
        const float inv = __expf(-0.14391156831212787f * (float)d);
        float sv, cv;
        __sincosf(p * inv, &sv, &cv);
        const float y1 = x1 * cv - x2 * sv;
        const float y2 = x2 * cv + x1 * sv;
        if (s < NHq) {
            Qb[((size_t)t * NHq + s) * Dh + d]      = bf16r(y1);
            Qb[((size_t)t * NHq + s) * Dh + d + 64] = bf16r(y2);
        } else {
            const int kvh = s - NHq;
            const int slot = slot_map[t];
            Kb[((size_t)t * NKVh + kvh) * Dh + d]      = bf16r(y1);
            Kb[((size_t)t * NKVh + kvh) * Dh + d + 64] = bf16r(y2);
            cacheOut[(size_t)slot * (NKVh * Dh) + kvh * Dh + d]      = y1;
            cacheOut[(size_t)slot * (NKVh * Dh) + kvh * Dh + d + 64] = y2;
        }
    } else {                                       // V: no RoPE; V^T + cache
        const int kvh = s - NHq - NKVh;
        const int slot = slot_map[t];
        const int b = t >> 10, stok = t & 1023;
        Vt[((size_t)(b * NKVh + kvh) * Dh + d) * Ss + stok]      = bf16r(x1);
        Vt[((size_t)(b * NKVh + kvh) * Dh + d + 64) * Ss + stok] = bf16r(x2);
        cacheOut[(size_t)NBLK * BSZ * NKVh * Dh +
                 (size_t)slot * (NKVh * Dh) + kvh * Dh + d]      = x1;
        cacheOut[(size_t)NBLK * BSZ * NKVh * Dh +
                 (size_t)slot * (NKVh * Dh) + kvh * Dh + d + 64] = x2;
    }
}

// ---------------- O-proj GEMM: C[M,N] = A[M,K] @ Bw[N,K]^T ----------------
// Tile 128x224, 4 waves (2M x 2N), wave 64x112, acc[4][7].
// Grid (3584/224=16, 4096/128=32) = 512 blocks exactly.
__global__ __launch_bounds__(256, 2) void gemm_bt(
    const ushort* __restrict__ A, const ushort* __restrict__ Bw,
    float* __restrict__ C, int N, int K)
{
    __shared__ ushort Asm_[128 * 32];
    __shared__ ushort Bsm_[224 * 32];
    const int tid  = threadIdx.x;
    const int wv   = tid >> 6;
    const int lane = tid & 63;
    const int quad = lane >> 4;
    const int l16  = lane & 15;
    const int m0 = blockIdx.y * 128;
    const int n0 = blockIdx.x * 224;
    const int wm = (wv >> 1) * 64;
    const int wn = (wv & 1) * 112;

    f4v zero = {0.f, 0.f, 0.f, 0.f};
    f4v acc[4][7];
    #pragma unroll
    for (int i = 0; i < 4; i++)
        #pragma unroll
        for (int j = 0; j < 7; j++) acc[i][j] = zero;

    const int swz = ((lane & 3) ^ ((lane >> 3) & 3)) * 8;
    const int rS  = lane >> 2;
    const ushort* gA = A  + (size_t)(m0 + rS) * K + swz;
    const ushort* gB = Bw + (size_t)(n0 + rS) * K + swz;
    const int fsw = ((l16 >> 1) & 3) * 8;

    for (int kt = 0; kt < K; kt += 32) {
        #pragma unroll
        for (int i = 0; i < 2; i++) {
            const int sl = wv + 4 * i;
            async_cp16(&Asm_[sl * 16 * 32], gA + (size_t)(sl * 16) * K + kt);
        }
        #pragma unroll
        for (int i = 0; i < 4; i++) {
            const int sl = wv + 4 * i;
            if (sl < 14)
                async_cp16(&Bsm_[sl * 16 * 32], gB + (size_t)(sl * 16) * K + kt);
        }
        __syncthreads();
        s8v af[4], bfr[7];
        #pragma unroll
        for (int i = 0; i < 4; i++)
            af[i] = *(const s8v*)&Asm_[(wm + i * 16 + l16) * 32 + ((quad * 8) ^ fsw)];
        #pragma unroll
        for (int j = 0; j < 7; j++)
            bfr[j] = *(const s8v*)&Bsm_[(wn + j * 16 + l16) * 32 + ((quad * 8) ^ fsw)];
        #pragma unroll
        for (int i = 0; i < 4; i++)
            #pragma unroll
            for (int j = 0; j < 7; j++)
                acc[i][j] = mfma16(af[i], bfr[j], acc[i][j]);
        __syncthreads();
    }

    #pragma unroll
    for (int i = 0; i < 4; i++) {
        const int m = m0 + wm + i * 16 + quad * 4;
        #pragma unroll
        for (int j = 0; j < 7; j++) {
            const int n = n0 + wn + j * 16 + l16;
            float* cp = C + (size_t)m * N + n;
            #pragma unroll
            for (int r = 0; r < 4; r++)
                cp[(size_t)r * N] = acc[i][j][r];
        }
    }
}

// ---------------- flash attention, S^T formulation (unchanged) ----------------
__global__ __launch_bounds__(256, 2) void attn(
    const ushort* __restrict__ Qb, const ushort* __restrict__ Kb,
    const ushort* __restrict__ Vt, ushort* __restrict__ ctx)
{
    __shared__ ushort Ksm[128 * 128];
    __shared__ ushort Vsm[128 * 128];

    const int tid  = threadIdx.x;
    const int w    = tid >> 6;
    const int lane = tid & 63;
    const int quad = lane >> 4;
    const int l16  = lane & 15;
    const int qt = (Ss / 128 - 1) - blockIdx.x;   // heavy blocks first
    const int h  = blockIdx.y;
    const int b  = blockIdx.z;
    const int kv = h / GRP;
    const int t0 = b * Ss + qt * 128;

    s8v qf[2][4];
    #pragma unroll
    for (int nt = 0; nt < 2; nt++)
        #pragma unroll
        for (int kd = 0; kd < 4; kd++)
            qf[nt][kd] = *(const s8v*)&Qb[((size_t)(t0 + w * 32 + nt * 16 + l16) * NHq + h) * Dh
                                          + kd * 32 + quad * 8];

    f4v zero = {0.f, 0.f, 0.f, 0.f};
    f4v o[2][8];
    #pragma unroll
    for (int nt = 0; nt < 2; nt++)
        #pragma unroll
        for (int dt = 0; dt < 8; dt++) o[nt][dt] = zero;
    float mstat[2] = {-1e30f, -1e30f};
    float dstat[2] = {0.f, 0.f};

    const int srow = lane >> 4;
    const int gch  = (lane & 15) ^ (w * 4 + srow);
    const ushort* gK = Kb + (size_t)(b * Ss) * (NKVh * Dh) + kv * Dh + gch * 8;
    const ushort* gV = Vt + (size_t)(b * NKVh + kv) * Dh * Ss + gch * 8;

    const int srcq0 = ((quad & 1) << 1) | (quad >> 1);
    const int addr0 = (srcq0 * 16 + l16) * 4;
    const int addr1 = ((srcq0 ^ 1) * 16 + l16) * 4;
    const bool oddq = (quad & 1);
    const bool lowq = (quad < 2);

    for (int kt = 0; kt <= qt; kt++) {
        const bool diag = (kt == qt);

        #pragma unroll
        for (int j = 0; j < 8; j++) {
            const int row = j * 16 + w * 4 + srow;
            async_cp16(&Ksm[(j * 16 + w * 4) * 128],
                       gK + (size_t)(kt * 128 + row) * (NKVh * Dh));
            async_cp16(&Vsm[(j * 16 + w * 4) * 128],
                       gV + (size_t)row * Ss + kt * 128);
        }
        __syncthreads();

        const int smax = diag ? (2 * w + 1) : 7;
        f4v sc[8][2];
        #pragma unroll
        for (int st = 0; st < 8; st++) { sc[st][0] = zero; sc[st][1] = zero; }
        #pragma unroll
        for (int st = 0; st < 8; st++) {
            if (st > smax) continue;
            #pragma unroll
            for (int kd = 0; kd < 4; kd++) {
                s8v kf = *(const s8v*)&Ksm[((st * 16 + l16) * 16 + ((kd * 4 + quad) ^ l16)) * 8];
                sc[st][0] = mfma16(kf, qf[0][kd], sc[st][0]);
                sc[st][1] = mfma16(kf, qf[1][kd], sc[st][1]);
            }
        }

        float alpha[2];
        #pragma unroll
        for (int nt = 0; nt < 2; nt++) {
            const int qcol = w * 32 + nt * 16 + l16;
            float rowm = -1e30f;
            #pragma unroll
            for (int st = 0; st < 8; st++) {
                if (st > smax) continue;
                #pragma unroll
                for (int r = 0; r < 4; r++) {
                    float v = sc[st][nt][r] * ATTN_SCALE;
                    if (diag && (st * 16 + quad * 4 + r > qcol)) v = -1e30f;
                    sc[st][nt][r] = v;
                    rowm = fmaxf(rowm, v);
                }
            }
            rowm = fmaxf(rowm, __shfl_xor(rowm, 16, 64));
            rowm = fmaxf(rowm, __shfl_xor(rowm, 32, 64));
            const float mn = fmaxf(mstat[nt], rowm);
            const float al = __expf(mstat[nt] - mn);
            float rs = 0.f;
            #pragma unroll
            for (int st = 0; st < 8; st++) {
                if (st > smax) continue;
                #pragma unroll
                for (int r = 0; r < 4; r++) {
                    const float p = __expf(sc[st][nt][r] - mn);
                    sc[st][nt][r] = p;
                    rs += p;
                }
            }
            rs += __shfl_xor(rs, 16, 64);
            rs += __shfl_xor(rs, 32, 64);
            dstat[nt] = dstat[nt] * al + rs;
            mstat[nt] = mn;
            alpha[nt] = al;
            #pragma unroll
            for (int dt = 0; dt < 8; dt++)
                #pragma unroll
                for (int r = 0; r < 4; r++) o[nt][dt][r] *= al;
        }

        const int spmax = diag ? w : 3;
        #pragma unroll
        for (int sp = 0; sp < 4; sp++) {
            if (sp > spmax) continue;
            s8v pf[2];
            #pragma unroll
            for (int nt = 0; nt < 2; nt++) {
                const uint32_t a01 = pkbf(sc[2 * sp][nt][0],     sc[2 * sp][nt][1]);
                const uint32_t a23 = pkbf(sc[2 * sp][nt][2],     sc[2 * sp][nt][3]);
                const uint32_t b01 = pkbf(sc[2 * sp + 1][nt][0], sc[2 * sp + 1][nt][1]);
                const uint32_t b23 = pkbf(sc[2 * sp + 1][nt][2], sc[2 * sp + 1][nt][3]);
                const int r0 = __builtin_amdgcn_ds_bpermute(addr0, (int)(oddq ? b01 : a01));
                const int r1 = __builtin_amdgcn_ds_bpermute(addr1, (int)(oddq ? a01 : b01));
                const int r2 = __builtin_amdgcn_ds_bpermute(addr0, (int)(oddq ? b23 : a23));
                const int r3 = __builtin_amdgcn_ds_bpermute(addr1, (int)(oddq ? a23 : b23));
                union { int d[4]; s8v v; } u;
                u.d[0] = lowq ? r0 : r1;
                u.d[1] = lowq ? r2 : r3;
                u.d[2] = lowq ? r1 : r0;
                u.d[3] = lowq ? r3 : r2;
                pf[nt] = u.v;
            }
            #pragma unroll
            for (int dt = 0; dt < 8; dt++) {
                s8v vf = *(const s8v*)&Vsm[((dt * 16 + l16) * 16 + ((sp * 4 + quad) ^ l16)) * 8];
                o[0][dt] = mfma16(vf, pf[0], o[0][dt]);
                o[1][dt] = mfma16(vf, pf[1], o[1][dt]);
            }
        }
        __syncthreads();
    }

    #pragma unroll
    for (int nt = 0; nt < 2; nt++) {
        const float inv = 1.0f / dstat[nt];
        const int trow = t0 + w * 32 + nt * 16 + l16;
        #pragma unroll
        for (int dt = 0; dt < 8; dt++) {
            ushort4 u;
            u.x = bf16r(o[nt][dt][0] * inv);
            u.y = bf16r(o[nt][dt][1] * inv);
            u.z = bf16r(o[nt][dt][2] * inv);
            u.w = bf16r(o[nt][dt][3] * inv);
            *(ushort4*)&ctx[(size_t)trow * Hd + h * Dh + dt * 16 + quad * 4] = u;
        }
    }
}

// ---------------- launch ----------------
extern "C" void kernel_launch(void* const* d_in, const int* in_sizes, int n_in,
                              void* d_out, int out_size, void* d_ws, size_t ws_size,
                              hipStream_t stream)
{
    const int*   positions = (const int*)d_in[0];
    const float* hidden    = (const float*)d_in[1];
    const float* kvc       = (const float*)d_in[2];
    const int*   slot_map  = (const int*)d_in[4];
    const float* w_qkv     = (const float*)d_in[7];
    const float* b_qkv     = (const float*)d_in[8];
    const float* w_o       = (const float*)d_in[9];

    float* out      = (float*)d_out;                 // (T, H) fp32
    float* cacheOut = out + (size_t)Tt * Hd;         // (2,NB,BS,NKV,D) fp32

    char* ws = (char*)d_ws;
    ushort* Xb    = (ushort*)(ws);                   // T*H bf16          29360128
    ushort* Wqkvb = (ushort*)(ws + 29360128);        // 4608*3584 bf16    33030144
    ushort* Wob   = (ushort*)(ws + 29360128);        // ALIAS: Wqkvb dead after gemm_qkv
    ushort* raw   = (ushort*)(ws + 62390272);        // T*4608 bf16       37748736
    ushort* Qb    = (ushort*)(ws + 100139008);       // T*NH*D bf16       29360128
    ushort* Kb    = (ushort*)(ws + 129499136);       // T*NKV*D bf16       4194304
    ushort* Vt    = (ushort*)(ws + 133693440);       // B*NKV*D*S bf16     4194304
    ushort* ctx   = Xb;                              // alias: Xb dead after gemm_qkv

    cvt_bf16<<<dim3(14336), 256, 0, stream>>>(hidden, Xb, 3670016);
    cvt_bf16<<<dim3(16128), 256, 0, stream>>>(w_qkv, Wqkvb, 4128768);
    copy_f4<<<dim3(8192), 256, 0, stream>>>(kvc, cacheOut, 2097152);
    gemm_qkv<<<dim3(QKVO / 288, Tt / 128), 256, 0, stream>>>(
        Xb, Wqkvb, b_qkv, raw);
    cvt_bf16<<<dim3(12544), 256, 0, stream>>>(w_o, Wob, 3211264);   // after gemm_qkv (alias)
    rope_scatter<<<dim3(Tt * 36 / 4), 256, 0, stream>>>(
        raw, positions, slot_map, Qb, Kb, Vt, cacheOut);
    attn<<<dim3(Ss / 128, NHq, Bb), 256, 0, stream>>>(Qb, Kb, Vt, ctx);
    gemm_bt<<<dim3(Hd / 224, Tt / 128), 256, 0, stream>>>(
        ctx, Wob, out, Hd, Hd);
}

// Round 5
// 631.589 us; speedup vs baseline: 1.0756x; 1.0152x over previous
//
#include <hip/hip_runtime.h>
#include <cstdint>
#include <cstddef>

// ---- problem constants ----
#define Hd    3584
#define NHq   28
#define NKVh  4
#define Dh    128
#define GRP   7
#define Bb    4
#define Ss    1024
#define Tt    4096
#define NBLK  512
#define BSZ   16
#define QKVO  4608
#define ATTN_SCALE 0.08838834764831845f  // 1/sqrt(128)

typedef short s8v __attribute__((ext_vector_type(8)));   // 8 x bf16 (4 VGPRs)
typedef float f4v __attribute__((ext_vector_type(4)));   // 4 x f32 accum

__device__ __forceinline__ ushort bf16r(float f) {       // RNE f32->bf16
    uint32_t u = __float_as_uint(f);
    u += 0x7fff + ((u >> 16) & 1);
    return (ushort)(u >> 16);
}

__device__ __forceinline__ float bf2f(ushort u) {
    uint32_t x = ((uint32_t)u) << 16;
    return __uint_as_float(x);
}

__device__ __forceinline__ uint32_t pkbf(float a, float b) {  // pack 2 bf16 -> b32
    return (uint32_t)bf16r(a) | ((uint32_t)bf16r(b) << 16);
}

__device__ __forceinline__ f4v mfma16(s8v a, s8v b, f4v c) {
    return __builtin_amdgcn_mfma_f32_16x16x32_bf16(a, b, c, 0, 0, 0);
}

// async global->LDS, 16B per lane; LDS dest = wave-uniform base + lane*16
__device__ __forceinline__ void async_cp16(ushort* lds, const ushort* g) {
    __builtin_amdgcn_global_load_lds(
        (const __attribute__((address_space(1))) uint32_t*)(uintptr_t)g,
        (__attribute__((address_space(3))) uint32_t*)(uintptr_t)lds,
        16, 0, 0);
}

// ---------------- fp32 -> bf16 convert (vectorized) ----------------
__global__ __launch_bounds__(256) void cvt_bf16(const float* __restrict__ src,
                                                ushort* __restrict__ dst, int n4) {
    int i = blockIdx.x * 256 + threadIdx.x;
    if (i >= n4) return;
    float4 f = ((const float4*)src)[i];
    ushort4 u;
    u.x = bf16r(f.x); u.y = bf16r(f.y); u.z = bf16r(f.z); u.w = bf16r(f.w);
    ((ushort4*)dst)[i] = u;
}

// ---------------- cache passthrough copy ----------------
__global__ __launch_bounds__(256) void copy_f4(const float* __restrict__ src,
                                               float* __restrict__ dst, int n4) {
    int i = blockIdx.x * 256 + threadIdx.x;
    if (i < n4) ((float4*)dst)[i] = ((const float4*)src)[i];
}

// ======================= GEMM design (R5) =======================
// R4 validated the LDS-BW model (MfmaUtil 40%, ~896 TF == the 2-barrier
// full-drain K-loop ceiling).  R5 keeps R4 geometry (2 blocks/CU, exact
// 512-block grids) and adds counted-vmcnt triple-buffer prefetch (T3/T4):
//   iter u: STAGE tile u+2 -> buf[(u+2)%3] | ds_read frags of buf[u%3]
//           -> lgkmcnt(0) -> setprio(1) MFMA cluster setprio(0)
//           -> vmcnt(n_w) -> s_barrier -> sched_barrier(0)
// n_w = this wave's staging issues/tile (qkv 7,7,6,6; bt 6,6,5,5); each
// wave's vmcnt(n_w) at end of iter u drains tile u+1's loads (the older
// n_w of its 2*n_w outstanding), so after the barrier iter u+1's reads are
// safe.  Buf overwrite at iter u hits buf[(u-1)%3] whose readers finished
// before their lgkmcnt(0)+barrier in iter u-1.  Tail: pf=false -> vmcnt(0).
// sched_barrier(0) after each s_barrier stops ds_read hoisting (rule #18).

// ---------------- QKV GEMM + bias: raw[M,4608] = X[M,K] @ Wqkv^T + b ------
// Tile 128x288, 4 waves (2M x 2N), wave 64x144, acc[4][9].
// Grid (4608/288=16, 4096/128=32) = 512 blocks.  LDS 79.9 KB (3 buf).
__global__ __launch_bounds__(256, 2) void gemm_qkv(
    const ushort* __restrict__ A, const ushort* __restrict__ Bw,
    const float* __restrict__ bias, ushort* __restrict__ raw)
{
    __shared__ ushort As[3][128 * 32];
    __shared__ ushort Bs[3][288 * 32];
    const int tid  = threadIdx.x;
    const int wv   = tid >> 6;
    const int lane = tid & 63;
    const int quad = lane >> 4;
    const int l16  = lane & 15;
    const int m0 = blockIdx.y * 128;
    const int n0 = blockIdx.x * 288;
    const int wm = (wv >> 1) * 64;
    const int wn = (wv & 1) * 144;

    f4v zero = {0.f, 0.f, 0.f, 0.f};
    f4v acc[4][9];
    #pragma unroll
    for (int i = 0; i < 4; i++)
        #pragma unroll
        for (int j = 0; j < 9; j++) acc[i][j] = zero;

    const int swz = ((lane & 3) ^ ((lane >> 3) & 3)) * 8;   // source chunk xor
    const int rS  = lane >> 2;                              // row in 16-row slot
    const ushort* gA = A  + (size_t)(m0 + rS) * Hd + swz;
    const ushort* gB = Bw + (size_t)(n0 + rS) * Hd + swz;
    const int fsw = ((l16 >> 1) & 3) * 8;                   // fragment chunk xor

    // A slots wv,wv+4 (2); B slots wv+4i<18 (waves 0,1: 5; 2,3: 4) -> 7,7,6,6
    #define QKV_STAGE(buf, kt)                                                  \
        {                                                                       \
            _Pragma("unroll")                                                   \
            for (int i_ = 0; i_ < 2; i_++) {                                    \
                const int sl = wv + 4 * i_;                                     \
                async_cp16(&As[buf][sl * 16 * 32], gA + (size_t)(sl * 16) * Hd + (kt)); \
            }                                                                   \
            _Pragma("unroll")                                                   \
            for (int i_ = 0; i_ < 5; i_++) {                                    \
                const int sl = wv + 4 * i_;                                     \
                if (sl < 18)                                                    \
                    async_cp16(&Bs[buf][sl * 16 * 32], gB + (size_t)(sl * 16) * Hd + (kt)); \
            }                                                                   \
        }

    QKV_STAGE(0, 0)
    QKV_STAGE(1, 32)
    if (wv < 2) asm volatile("s_waitcnt vmcnt(7)" ::: "memory");
    else        asm volatile("s_waitcnt vmcnt(6)" ::: "memory");
    __builtin_amdgcn_s_barrier();
    __builtin_amdgcn_sched_barrier(0);

    const int NT = Hd / 32;            // 112
    for (int t = 0; t < NT; t++) {
        const ushort* Ac = As[t % 3];
        const ushort* Bc = Bs[t % 3];
        const int nb = (t + 2) % 3;
        const bool pf = (t + 2 < NT);
        if (pf) QKV_STAGE(nb, (t + 2) * 32)

        s8v af[4], bfr[9];
        #pragma unroll
        for (int i = 0; i < 4; i++)
            af[i] = *(const s8v*)&Ac[(wm + i * 16 + l16) * 32 + ((quad * 8) ^ fsw)];
        #pragma unroll
        for (int j = 0; j < 9; j++)
            bfr[j] = *(const s8v*)&Bc[(wn + j * 16 + l16) * 32 + ((quad * 8) ^ fsw)];
        asm volatile("s_waitcnt lgkmcnt(0)" ::: "memory");
        __builtin_amdgcn_sched_barrier(0);
        __builtin_amdgcn_s_setprio(1);
        #pragma unroll
        for (int i = 0; i < 4; i++)
            #pragma unroll
            for (int j = 0; j < 9; j++)
                acc[i][j] = mfma16(af[i], bfr[j], acc[i][j]);
        __builtin_amdgcn_s_setprio(0);
        __builtin_amdgcn_sched_barrier(0);
        if (pf) {
            if (wv < 2) asm volatile("s_waitcnt vmcnt(7)" ::: "memory");
            else        asm volatile("s_waitcnt vmcnt(6)" ::: "memory");
        } else {
            asm volatile("s_waitcnt vmcnt(0)" ::: "memory");
        }
        __builtin_amdgcn_s_barrier();
        __builtin_amdgcn_sched_barrier(0);
    }
    #undef QKV_STAGE

    // epilogue: + bias, write bf16 raw
    float bv[9];
    #pragma unroll
    for (int j = 0; j < 9; j++) bv[j] = bias[n0 + wn + j * 16 + l16];
    #pragma unroll
    for (int i = 0; i < 4; i++) {
        const int m = m0 + wm + i * 16 + quad * 4;
        #pragma unroll
        for (int j = 0; j < 9; j++) {
            const int n = n0 + wn + j * 16 + l16;
            #pragma unroll
            for (int r = 0; r < 4; r++)
                raw[(size_t)(m + r) * QKVO + n] = bf16r(acc[i][j][r] + bv[j]);
        }
    }
}

// ---------------- RoPE for Q/K + scatter ----------------
// 32 slots/token (power of 2): s<28 -> Q, else K.
__global__ __launch_bounds__(256) void rope_qk(
    const ushort* __restrict__ raw, const int* __restrict__ pos,
    const int* __restrict__ slot_map,
    ushort* __restrict__ Qb, ushort* __restrict__ Kb, float* __restrict__ cacheOut)
{
    const int wv  = threadIdx.x >> 6;
    const int d   = threadIdx.x & 63;
    const int job = blockIdx.x * 4 + wv;           // t*32 + s
    const int t   = job >> 5;
    const int s   = job & 31;

    const float x1 = bf2f(raw[(size_t)t * QKVO + s * 128 + d]);
    const float x2 = bf2f(raw[(size_t)t * QKVO + s * 128 + d + 64]);

    const float p = (float)pos[t];
    const float inv = __expf(-0.14391156831212787f * (float)d);
    float sv, cv;
    __sincosf(p * inv, &sv, &cv);
    const float y1 = x1 * cv - x2 * sv;
    const float y2 = x2 * cv + x1 * sv;
    if (s < NHq) {
        Qb[((size_t)t * NHq + s) * Dh + d]      = bf16r(y1);
        Qb[((size_t)t * NHq + s) * Dh + d + 64] = bf16r(y2);
    } else {
        const int kvh = s - NHq;
        const int slot = slot_map[t];
        Kb[((size_t)t * NKVh + kvh) * Dh + d]      = bf16r(y1);
        Kb[((size_t)t * NKVh + kvh) * Dh + d + 64] = bf16r(y2);
        cacheOut[(size_t)slot * (NKVh * Dh) + kvh * Dh + d]      = y1;
        cacheOut[(size_t)slot * (NKVh * Dh) + kvh * Dh + d + 64] = y2;
    }
}

// ---------------- V scatter: LDS transpose -> coalesced V^T + cache -------
// Block = 64 tokens x 1 kv head.  raw read + cache write coalesced; Vt row
// write = 64 contiguous tokens (128B).  Grid (16, NKVh, Bb) = 256 blocks.
__global__ __launch_bounds__(256) void v_scatter(
    const ushort* __restrict__ raw, const int* __restrict__ slot_map,
    ushort* __restrict__ Vt, float* __restrict__ cacheOut)
{
    __shared__ ushort vs[64][130];                 // +2 pad: 2-way banks (free)
    const int tb  = blockIdx.x;
    const int kvh = blockIdx.y;
    const int b   = blockIdx.z;
    const int wv  = threadIdx.x >> 6;              // 0..3
    const int c   = threadIdx.x & 63;
    const int t0  = b * Ss + tb * 64;

    #pragma unroll
    for (int it = 0; it < 16; it++) {
        const int tr = wv + 4 * it;                // one 128-d row per wave
        const int t  = t0 + tr;
        ushort2 u = *(const ushort2*)&raw[(size_t)t * QKVO + (NHq + NKVh + kvh) * 128 + c * 2];
        *(ushort2*)&vs[tr][c * 2] = u;
        const int slot = slot_map[t];
        float2 f;
        f.x = bf2f(u.x);
        f.y = bf2f(u.y);
        *(float2*)&cacheOut[(size_t)NBLK * BSZ * NKVh * Dh +
                            (size_t)slot * (NKVh * Dh) + kvh * Dh + c * 2] = f;
    }
    __syncthreads();
    const int stok0 = tb * 64;
    #pragma unroll
    for (int it = 0; it < 32; it++) {
        const int d = wv * 32 + it;
        Vt[((size_t)(b * NKVh + kvh) * Dh + d) * Ss + stok0 + c] = vs[c][d];
    }
}

// ---------------- O-proj GEMM: C[M,N] = A[M,K] @ Bw[N,K]^T ----------------
// Tile 128x224, 4 waves (2M x 2N), wave 64x112, acc[4][7].
// Grid (3584/224=16, 4096/128=32) = 512 blocks.  LDS 67.6 KB (3 buf).
__global__ __launch_bounds__(256, 2) void gemm_bt(
    const ushort* __restrict__ A, const ushort* __restrict__ Bw,
    float* __restrict__ C, int N, int K)
{
    __shared__ ushort As[3][128 * 32];
    __shared__ ushort Bs[3][224 * 32];
    const int tid  = threadIdx.x;
    const int wv   = tid >> 6;
    const int lane = tid & 63;
    const int quad = lane >> 4;
    const int l16  = lane & 15;
    const int m0 = blockIdx.y * 128;
    const int n0 = blockIdx.x * 224;
    const int wm = (wv >> 1) * 64;
    const int wn = (wv & 1) * 112;

    f4v zero = {0.f, 0.f, 0.f, 0.f};
    f4v acc[4][7];
    #pragma unroll
    for (int i = 0; i < 4; i++)
        #pragma unroll
        for (int j = 0; j < 7; j++) acc[i][j] = zero;

    const int swz = ((lane & 3) ^ ((lane >> 3) & 3)) * 8;
    const int rS  = lane >> 2;
    const ushort* gA = A  + (size_t)(m0 + rS) * K + swz;
    const ushort* gB = Bw + (size_t)(n0 + rS) * K + swz;
    const int fsw = ((l16 >> 1) & 3) * 8;

    // A slots wv,wv+4 (2); B slots wv+4i<14 (waves 0,1: 4; 2,3: 3) -> 6,6,5,5
    #define BT_STAGE(buf, kt)                                                   \
        {                                                                       \
            _Pragma("unroll")                                                   \
            for (int i_ = 0; i_ < 2; i_++) {                                    \
                const int sl = wv + 4 * i_;                                     \
                async_cp16(&As[buf][sl * 16 * 32], gA + (size_t)(sl * 16) * K + (kt)); \
            }                                                                   \
            _Pragma("unroll")                                                   \
            for (int i_ = 0; i_ < 4; i_++) {                                    \
                const int sl = wv + 4 * i_;                                     \
                if (sl < 14)                                                    \
                    async_cp16(&Bs[buf][sl * 16 * 32], gB + (size_t)(sl * 16) * K + (kt)); \
            }                                                                   \
        }

    BT_STAGE(0, 0)
    BT_STAGE(1, 32)
    if (wv < 2) asm volatile("s_waitcnt vmcnt(6)" ::: "memory");
    else        asm volatile("s_waitcnt vmcnt(5)" ::: "memory");
    __builtin_amdgcn_s_barrier();
    __builtin_amdgcn_sched_barrier(0);

    const int NT = K / 32;
    for (int t = 0; t < NT; t++) {
        const ushort* Ac = As[t % 3];
        const ushort* Bc = Bs[t % 3];
        const int nb = (t + 2) % 3;
        const bool pf = (t + 2 < NT);
        if (pf) BT_STAGE(nb, (t + 2) * 32)

        s8v af[4], bfr[7];
        #pragma unroll
        for (int i = 0; i < 4; i++)
            af[i] = *(const s8v*)&Ac[(wm + i * 16 + l16) * 32 + ((quad * 8) ^ fsw)];
        #pragma unroll
        for (int j = 0; j < 7; j++)
            bfr[j] = *(const s8v*)&Bc[(wn + j * 16 + l16) * 32 + ((quad * 8) ^ fsw)];
        asm volatile("s_waitcnt lgkmcnt(0)" ::: "memory");
        __builtin_amdgcn_sched_barrier(0);
        __builtin_amdgcn_s_setprio(1);
        #pragma unroll
        for (int i = 0; i < 4; i++)
            #pragma unroll
            for (int j = 0; j < 7; j++)
                acc[i][j] = mfma16(af[i], bfr[j], acc[i][j]);
        __builtin_amdgcn_s_setprio(0);
        __builtin_amdgcn_sched_barrier(0);
        if (pf) {
            if (wv < 2) asm volatile("s_waitcnt vmcnt(6)" ::: "memory");
            else        asm volatile("s_waitcnt vmcnt(5)" ::: "memory");
        } else {
            asm volatile("s_waitcnt vmcnt(0)" ::: "memory");
        }
        __builtin_amdgcn_s_barrier();
        __builtin_amdgcn_sched_barrier(0);
    }
    #undef BT_STAGE

    #pragma unroll
    for (int i = 0; i < 4; i++) {
        const int m = m0 + wm + i * 16 + quad * 4;
        #pragma unroll
        for (int j = 0; j < 7; j++) {
            const int n = n0 + wn + j * 16 + l16;
            float* cp = C + (size_t)m * N + n;
            #pragma unroll
            for (int r = 0; r < 4; r++)
                cp[(size_t)r * N] = acc[i][j][r];
        }
    }
}

// ---------------- flash attention, S^T formulation (unchanged) ----------------
__global__ __launch_bounds__(256, 2) void attn(
    const ushort* __restrict__ Qb, const ushort* __restrict__ Kb,
    const ushort* __restrict__ Vt, ushort* __restrict__ ctx)
{
    __shared__ ushort Ksm[128 * 128];
    __shared__ ushort Vsm[128 * 128];

    const int tid  = threadIdx.x;
    const int w    = tid >> 6;
    const int lane = tid & 63;
    const int quad = lane >> 4;
    const int l16  = lane & 15;
    const int qt = (Ss / 128 - 1) - blockIdx.x;   // heavy blocks first
    const int h  = blockIdx.y;
    const int b  = blockIdx.z;
    const int kv = h / GRP;
    const int t0 = b * Ss + qt * 128;

    s8v qf[2][4];
    #pragma unroll
    for (int nt = 0; nt < 2; nt++)
        #pragma unroll
        for (int kd = 0; kd < 4; kd++)
            qf[nt][kd] = *(const s8v*)&Qb[((size_t)(t0 + w * 32 + nt * 16 + l16) * NHq + h) * Dh
                                          + kd * 32 + quad * 8];

    f4v zero = {0.f, 0.f, 0.f, 0.f};
    f4v o[2][8];
    #pragma unroll
    for (int nt = 0; nt < 2; nt++)
        #pragma unroll
        for (int dt = 0; dt < 8; dt++) o[nt][dt] = zero;
    float mstat[2] = {-1e30f, -1e30f};
    float dstat[2] = {0.f, 0.f};

    const int srow = lane >> 4;
    const int gch  = (lane & 15) ^ (w * 4 + srow);
    const ushort* gK = Kb + (size_t)(b * Ss) * (NKVh * Dh) + kv * Dh + gch * 8;
    const ushort* gV = Vt + (size_t)(b * NKVh + kv) * Dh * Ss + gch * 8;

    const int srcq0 = ((quad & 1) << 1) | (quad >> 1);
    const int addr0 = (srcq0 * 16 + l16) * 4;
    const int addr1 = ((srcq0 ^ 1) * 16 + l16) * 4;
    const bool oddq = (quad & 1);
    const bool lowq = (quad < 2);

    for (int kt = 0; kt <= qt; kt++) {
        const bool diag = (kt == qt);

        #pragma unroll
        for (int j = 0; j < 8; j++) {
            const int row = j * 16 + w * 4 + srow;
            async_cp16(&Ksm[(j * 16 + w * 4) * 128],
                       gK + (size_t)(kt * 128 + row) * (NKVh * Dh));
            async_cp16(&Vsm[(j * 16 + w * 4) * 128],
                       gV + (size_t)row * Ss + kt * 128);
        }
        __syncthreads();

        const int smax = diag ? (2 * w + 1) : 7;
        f4v sc[8][2];
        #pragma unroll
        for (int st = 0; st < 8; st++) { sc[st][0] = zero; sc[st][1] = zero; }
        #pragma unroll
        for (int st = 0; st < 8; st++) {
            if (st > smax) continue;
            #pragma unroll
            for (int kd = 0; kd < 4; kd++) {
                s8v kf = *(const s8v*)&Ksm[((st * 16 + l16) * 16 + ((kd * 4 + quad) ^ l16)) * 8];
                sc[st][0] = mfma16(kf, qf[0][kd], sc[st][0]);
                sc[st][1] = mfma16(kf, qf[1][kd], sc[st][1]);
            }
        }

        float alpha[2];
        #pragma unroll
        for (int nt = 0; nt < 2; nt++) {
            const int qcol = w * 32 + nt * 16 + l16;
            float rowm = -1e30f;
            #pragma unroll
            for (int st = 0; st < 8; st++) {
                if (st > smax) continue;
                #pragma unroll
                for (int r = 0; r < 4; r++) {
                    float v = sc[st][nt][r] * ATTN_SCALE;
                    if (diag && (st * 16 + quad * 4 + r > qcol)) v = -1e30f;
                    sc[st][nt][r] = v;
                    rowm = fmaxf(rowm, v);
                }
            }
            rowm = fmaxf(rowm, __shfl_xor(rowm, 16, 64));
            rowm = fmaxf(rowm, __shfl_xor(rowm, 32, 64));
            const float mn = fmaxf(mstat[nt], rowm);
            const float al = __expf(mstat[nt] - mn);
            float rs = 0.f;
            #pragma unroll
            for (int st = 0; st < 8; st++) {
                if (st > smax) continue;
                #pragma unroll
                for (int r = 0; r < 4; r++) {
                    const float p = __expf(sc[st][nt][r] - mn);
                    sc[st][nt][r] = p;
                    rs += p;
                }
            }
            rs += __shfl_xor(rs, 16, 64);
            rs += __shfl_xor(rs, 32, 64);
            dstat[nt] = dstat[nt] * al + rs;
            mstat[nt] = mn;
            alpha[nt] = al;
            #pragma unroll
            for (int dt = 0; dt < 8; dt++)
                #pragma unroll
                for (int r = 0; r < 4; r++) o[nt][dt][r] *= al;
        }

        const int spmax = diag ? w : 3;
        #pragma unroll
        for (int sp = 0; sp < 4; sp++) {
            if (sp > spmax) continue;
            s8v pf[2];
            #pragma unroll
            for (int nt = 0; nt < 2; nt++) {
                const uint32_t a01 = pkbf(sc[2 * sp][nt][0],     sc[2 * sp][nt][1]);
                const uint32_t a23 = pkbf(sc[2 * sp][nt][2],     sc[2 * sp][nt][3]);
                const uint32_t b01 = pkbf(sc[2 * sp + 1][nt][0], sc[2 * sp + 1][nt][1]);
                const uint32_t b23 = pkbf(sc[2 * sp + 1][nt][2], sc[2 * sp + 1][nt][3]);
                const int r0 = __builtin_amdgcn_ds_bpermute(addr0, (int)(oddq ? b01 : a01));
                const int r1 = __builtin_amdgcn_ds_bpermute(addr1, (int)(oddq ? a01 : b01));
                const int r2 = __builtin_amdgcn_ds_bpermute(addr0, (int)(oddq ? b23 : a23));
                const int r3 = __builtin_amdgcn_ds_bpermute(addr1, (int)(oddq ? a23 : b23));
                union { int d[4]; s8v v; } u;
                u.d[0] = lowq ? r0 : r1;
                u.d[1] = lowq ? r2 : r3;
                u.d[2] = lowq ? r1 : r0;
                u.d[3] = lowq ? r3 : r2;
                pf[nt] = u.v;
            }
            #pragma unroll
            for (int dt = 0; dt < 8; dt++) {
                s8v vf = *(const s8v*)&Vsm[((dt * 16 + l16) * 16 + ((sp * 4 + quad) ^ l16)) * 8];
                o[0][dt] = mfma16(vf, pf[0], o[0][dt]);
                o[1][dt] = mfma16(vf, pf[1], o[1][dt]);
            }
        }
        __syncthreads();
    }

    #pragma unroll
    for (int nt = 0; nt < 2; nt++) {
        const float inv = 1.0f / dstat[nt];
        const int trow = t0 + w * 32 + nt * 16 + l16;
        #pragma unroll
        for (int dt = 0; dt < 8; dt++) {
            ushort4 u;
            u.x = bf16r(o[nt][dt][0] * inv);
            u.y = bf16r(o[nt][dt][1] * inv);
            u.z = bf16r(o[nt][dt][2] * inv);
            u.w = bf16r(o[nt][dt][3] * inv);
            *(ushort4*)&ctx[(size_t)trow * Hd + h * Dh + dt * 16 + quad * 4] = u;
        }
    }
}

// ---------------- launch ----------------
extern "C" void kernel_launch(void* const* d_in, const int* in_sizes, int n_in,
                              void* d_out, int out_size, void* d_ws, size_t ws_size,
                              hipStream_t stream)
{
    const int*   positions = (const int*)d_in[0];
    const float* hidden    = (const float*)d_in[1];
    const float* kvc       = (const float*)d_in[2];
    const int*   slot_map  = (const int*)d_in[4];
    const float* w_qkv     = (const float*)d_in[7];
    const float* b_qkv     = (const float*)d_in[8];
    const float* w_o       = (const float*)d_in[9];

    float* out      = (float*)d_out;                 // (T, H) fp32
    float* cacheOut = out + (size_t)Tt * Hd;         // (2,NB,BS,NKV,D) fp32

    char* ws = (char*)d_ws;
    ushort* Xb    = (ushort*)(ws);                   // T*H bf16          29360128
    ushort* Wqkvb = (ushort*)(ws + 29360128);        // 4608*3584 bf16    33030144
    ushort* Wob   = (ushort*)(ws + 29360128);        // ALIAS: Wqkvb dead after gemm_qkv
    ushort* raw   = (ushort*)(ws + 62390272);        // T*4608 bf16       37748736
    ushort* Qb    = (ushort*)(ws + 100139008);       // T*NH*D bf16       29360128
    ushort* Kb    = (ushort*)(ws + 129499136);       // T*NKV*D bf16       4194304
    ushort* Vt    = (ushort*)(ws + 133693440);       // B*NKV*D*S bf16     4194304
    ushort* ctx   = Xb;                              // alias: Xb dead after gemm_qkv

    cvt_bf16<<<dim3(14336), 256, 0, stream>>>(hidden, Xb, 3670016);
    cvt_bf16<<<dim3(16128), 256, 0, stream>>>(w_qkv, Wqkvb, 4128768);
    copy_f4<<<dim3(8192), 256, 0, stream>>>(kvc, cacheOut, 2097152);
    gemm_qkv<<<dim3(QKVO / 288, Tt / 128), 256, 0, stream>>>(
        Xb, Wqkvb, b_qkv, raw);
    cvt_bf16<<<dim3(12544), 256, 0, stream>>>(w_o, Wob, 3211264);   // after gemm_qkv (alias)
    rope_qk<<<dim3(Tt * 32 / 4), 256, 0, stream>>>(
        raw, positions, slot_map, Qb, Kb, cacheOut);
    v_scatter<<<dim3(16, NKVh, Bb), 256, 0, stream>>>(
        raw, slot_map, Vt, cacheOut);
    attn<<<dim3(Ss / 128, NHq, Bb), 256, 0, stream>>>(Qb, Kb, Vt, ctx);
    gemm_bt<<<dim3(Hd / 224, Tt / 128), 256, 0, stream>>>(
        ctx, Wob, out, Hd, Hd);
}

// Round 7
// 620.824 us; speedup vs baseline: 1.0942x; 1.0173x over previous
//
#include <hip/hip_runtime.h>
#include <cstdint>
#include <cstddef>

// ---- problem constants ----
#define Hd    3584
#define NHq   28
#define NKVh  4
#define Dh    128
#define GRP   7
#define Bb    4
#define Ss    1024
#define Tt    4096
#define NBLK  512
#define BSZ   16
#define QKVO  4608
#define ATTN_SCALE 0.08838834764831845f  // 1/sqrt(128)

typedef short s8v __attribute__((ext_vector_type(8)));   // 8 x bf16 (4 VGPRs)
typedef float f4v __attribute__((ext_vector_type(4)));   // 4 x f32 accum

__device__ __forceinline__ ushort bf16r(float f) {       // RNE f32->bf16
    uint32_t u = __float_as_uint(f);
    u += 0x7fff + ((u >> 16) & 1);
    return (ushort)(u >> 16);
}

__device__ __forceinline__ float bf2f(ushort u) {
    uint32_t x = ((uint32_t)u) << 16;
    return __uint_as_float(x);
}

__device__ __forceinline__ uint32_t pkbf(float a, float b) {  // pack 2 bf16 -> b32
    return (uint32_t)bf16r(a) | ((uint32_t)bf16r(b) << 16);
}

__device__ __forceinline__ f4v mfma16(s8v a, s8v b, f4v c) {
    return __builtin_amdgcn_mfma_f32_16x16x32_bf16(a, b, c, 0, 0, 0);
}

// async global->LDS, 16B per lane; LDS dest = wave-uniform base + lane*16
__device__ __forceinline__ void async_cp16(ushort* lds, const ushort* g) {
    __builtin_amdgcn_global_load_lds(
        (const __attribute__((address_space(1))) uint32_t*)(uintptr_t)g,
        (__attribute__((address_space(3))) uint32_t*)(uintptr_t)lds,
        16, 0, 0);
}

// ---------------- fused prologue: cvt(hidden) + cvt(w_qkv) + cache copy ----
#define PREP_N1 3670016                   // hidden f4 count
#define PREP_N2 4128768                   // w_qkv  f4 count
#define PREP_N3 2097152                   // cache  f4 count
__global__ __launch_bounds__(256) void prep(
    const float* __restrict__ hidden, const float* __restrict__ wqkv,
    const float* __restrict__ kvc,
    ushort* __restrict__ Xb, ushort* __restrict__ Wqkvb, float* __restrict__ cacheOut)
{
    int i = blockIdx.x * 256 + threadIdx.x;
    if (i < PREP_N1) {
        float4 f = ((const float4*)hidden)[i];
        ushort4 u;
        u.x = bf16r(f.x); u.y = bf16r(f.y); u.z = bf16r(f.z); u.w = bf16r(f.w);
        ((ushort4*)Xb)[i] = u;
    } else if (i < PREP_N1 + PREP_N2) {
        i -= PREP_N1;
        float4 f = ((const float4*)wqkv)[i];
        ushort4 u;
        u.x = bf16r(f.x); u.y = bf16r(f.y); u.z = bf16r(f.z); u.w = bf16r(f.w);
        ((ushort4*)Wqkvb)[i] = u;
    } else {
        i -= PREP_N1 + PREP_N2;
        if (i < PREP_N3) ((float4*)cacheOut)[i] = ((const float4*)kvc)[i];
    }
}

// ---------------- fp32 -> bf16 convert (vectorized) ----------------
__global__ __launch_bounds__(256) void cvt_bf16(const float* __restrict__ src,
                                                ushort* __restrict__ dst, int n4) {
    int i = blockIdx.x * 256 + threadIdx.x;
    if (i >= n4) return;
    float4 f = ((const float4*)src)[i];
    ushort4 u;
    u.x = bf16r(f.x); u.y = bf16r(f.y); u.z = bf16r(f.z); u.w = bf16r(f.w);
    ((ushort4*)dst)[i] = u;
}

// ======================= GEMM design (R6/R7) =======================
// R5 cycle model (validated): per CU per K-tile, MFMA 1397 cyc + DS 1872 cyc
// SUMMED (3140 measured) because barrier lockstep + full lgkm drain makes all
// waves alternate read-phase / MFMA-phase together.  R6 overlaps them within
// the wave: split reads into g1 (af+bfr0-3) / g2 (rest), wait lgkmcnt(g2cnt)
// -> MFMA g1 runs while g2 drains -> lgkmcnt(0) -> MFMA g2.  Shell (3-buffer,
// counted vmcnt, 1 barrier/tile) is exactly R5's proven structure.
// Counted-lgkm validity: global_load_lds increments vmcnt ONLY, so the staged
// loads between g1 and g2 don't perturb the lgkm count; DS ops retire in
// order per wave.  R7 = identical resubmission (R6 bench was infra failure).

// ---------------- QKV GEMM + bias: raw[M,4608] = X[M,K] @ Wqkv^T + b ------
// Tile 128x288, 4 waves (2M x 2N), wave 64x144, acc[4][9].
// Grid (4608/288=16, 4096/128=32) = 512 blocks.  LDS 79.9 KB (3 buf).
__global__ __launch_bounds__(256, 2) void gemm_qkv(
    const ushort* __restrict__ A, const ushort* __restrict__ Bw,
    const float* __restrict__ bias, ushort* __restrict__ raw)
{
    __shared__ ushort As[3][128 * 32];
    __shared__ ushort Bs[3][288 * 32];
    const int tid  = threadIdx.x;
    const int wv   = tid >> 6;
    const int lane = tid & 63;
    const int quad = lane >> 4;
    const int l16  = lane & 15;
    const int m0 = blockIdx.y * 128;
    const int n0 = blockIdx.x * 288;
    const int wm = (wv >> 1) * 64;
    const int wn = (wv & 1) * 144;

    f4v zero = {0.f, 0.f, 0.f, 0.f};
    f4v acc[4][9];
    #pragma unroll
    for (int i = 0; i < 4; i++)
        #pragma unroll
        for (int j = 0; j < 9; j++) acc[i][j] = zero;

    const int swz = ((lane & 3) ^ ((lane >> 3) & 3)) * 8;   // source chunk xor
    const int rS  = lane >> 2;                              // row in 16-row slot
    const ushort* gA = A  + (size_t)(m0 + rS) * Hd + swz;
    const ushort* gB = Bw + (size_t)(n0 + rS) * Hd + swz;
    const int fsw = ((l16 >> 1) & 3) * 8;                   // fragment chunk xor

    // A slots wv,wv+4 (2); B slots wv+4i<18 (waves 0,1: 5; 2,3: 4) -> 7,7,6,6
    #define QKV_STAGE(buf, kt)                                                  \
        {                                                                       \
            _Pragma("unroll")                                                   \
            for (int i_ = 0; i_ < 2; i_++) {                                    \
                const int sl = wv + 4 * i_;                                     \
                async_cp16(&As[buf][sl * 16 * 32], gA + (size_t)(sl * 16) * Hd + (kt)); \
            }                                                                   \
            _Pragma("unroll")                                                   \
            for (int i_ = 0; i_ < 5; i_++) {                                    \
                const int sl = wv + 4 * i_;                                     \
                if (sl < 18)                                                    \
                    async_cp16(&Bs[buf][sl * 16 * 32], gB + (size_t)(sl * 16) * Hd + (kt)); \
            }                                                                   \
        }

    QKV_STAGE(0, 0)
    QKV_STAGE(1, 32)
    if (wv < 2) asm volatile("s_waitcnt vmcnt(7)" ::: "memory");
    else        asm volatile("s_waitcnt vmcnt(6)" ::: "memory");
    __builtin_amdgcn_s_barrier();
    __builtin_amdgcn_sched_barrier(0);

    const int NT = Hd / 32;            // 112
    for (int t = 0; t < NT; t++) {
        const ushort* Ac = As[t % 3];
        const ushort* Bc = Bs[t % 3];
        const int nb = (t + 2) % 3;
        const bool pf = (t + 2 < NT);

        s8v af[4], bfr[9];
        // ---- read group 1: af0-3, bfr0-3 (8 ds_reads) ----
        #pragma unroll
        for (int i = 0; i < 4; i++)
            af[i] = *(const s8v*)&Ac[(wm + i * 16 + l16) * 32 + ((quad * 8) ^ fsw)];
        #pragma unroll
        for (int j = 0; j < 4; j++)
            bfr[j] = *(const s8v*)&Bc[(wn + j * 16 + l16) * 32 + ((quad * 8) ^ fsw)];
        __builtin_amdgcn_sched_barrier(0);      // g1 issued before stage/g2
        if (pf) QKV_STAGE(nb, (t + 2) * 32)     // vmem only; lgkm unaffected
        // ---- read group 2: bfr4-8 (5 ds_reads) ----
        #pragma unroll
        for (int j = 4; j < 9; j++)
            bfr[j] = *(const s8v*)&Bc[(wn + j * 16 + l16) * 32 + ((quad * 8) ^ fsw)];
        asm volatile("s_waitcnt lgkmcnt(5)" ::: "memory");   // g1 landed (13-8=5 left)
        __builtin_amdgcn_sched_barrier(0);
        __builtin_amdgcn_s_setprio(1);
        #pragma unroll
        for (int i = 0; i < 4; i++)             // MFMA g1 (16) || g2 drains
            #pragma unroll
            for (int j = 0; j < 4; j++)
                acc[i][j] = mfma16(af[i], bfr[j], acc[i][j]);
        asm volatile("s_waitcnt lgkmcnt(0)" ::: "memory");   // g2 landed
        __builtin_amdgcn_sched_barrier(0);
        #pragma unroll
        for (int i = 0; i < 4; i++)             // MFMA g2 (20)
            #pragma unroll
            for (int j = 4; j < 9; j++)
                acc[i][j] = mfma16(af[i], bfr[j], acc[i][j]);
        __builtin_amdgcn_s_setprio(0);
        __builtin_amdgcn_sched_barrier(0);
        if (pf) {
            if (wv < 2) asm volatile("s_waitcnt vmcnt(7)" ::: "memory");
            else        asm volatile("s_waitcnt vmcnt(6)" ::: "memory");
        } else {
            asm volatile("s_waitcnt vmcnt(0)" ::: "memory");
        }
        __builtin_amdgcn_s_barrier();
        __builtin_amdgcn_sched_barrier(0);
    }
    #undef QKV_STAGE

    // epilogue: + bias, write bf16 raw
    float bv[9];
    #pragma unroll
    for (int j = 0; j < 9; j++) bv[j] = bias[n0 + wn + j * 16 + l16];
    #pragma unroll
    for (int i = 0; i < 4; i++) {
        const int m = m0 + wm + i * 16 + quad * 4;
        #pragma unroll
        for (int j = 0; j < 9; j++) {
            const int n = n0 + wn + j * 16 + l16;
            #pragma unroll
            for (int r = 0; r < 4; r++)
                raw[(size_t)(m + r) * QKVO + n] = bf16r(acc[i][j][r] + bv[j]);
        }
    }
}

// ---------------- RoPE for Q/K + scatter ----------------
// 32 slots/token (power of 2): s<28 -> Q, else K.
__global__ __launch_bounds__(256) void rope_qk(
    const ushort* __restrict__ raw, const int* __restrict__ pos,
    const int* __restrict__ slot_map,
    ushort* __restrict__ Qb, ushort* __restrict__ Kb, float* __restrict__ cacheOut)
{
    const int wv  = threadIdx.x >> 6;
    const int d   = threadIdx.x & 63;
    const int job = blockIdx.x * 4 + wv;           // t*32 + s
    const int t   = job >> 5;
    const int s   = job & 31;

    const float x1 = bf2f(raw[(size_t)t * QKVO + s * 128 + d]);
    const float x2 = bf2f(raw[(size_t)t * QKVO + s * 128 + d + 64]);

    const float p = (float)pos[t];
    const float inv = __expf(-0.14391156831212787f * (float)d);
    float sv, cv;
    __sincosf(p * inv, &sv, &cv);
    const float y1 = x1 * cv - x2 * sv;
    const float y2 = x2 * cv + x1 * sv;
    if (s < NHq) {
        Qb[((size_t)t * NHq + s) * Dh + d]      = bf16r(y1);
        Qb[((size_t)t * NHq + s) * Dh + d + 64] = bf16r(y2);
    } else {
        const int kvh = s - NHq;
        const int slot = slot_map[t];
        Kb[((size_t)t * NKVh + kvh) * Dh + d]      = bf16r(y1);
        Kb[((size_t)t * NKVh + kvh) * Dh + d + 64] = bf16r(y2);
        cacheOut[(size_t)slot * (NKVh * Dh) + kvh * Dh + d]      = y1;
        cacheOut[(size_t)slot * (NKVh * Dh) + kvh * Dh + d + 64] = y2;
    }
}

// ---------------- V scatter: LDS transpose -> coalesced V^T + cache -------
__global__ __launch_bounds__(256) void v_scatter(
    const ushort* __restrict__ raw, const int* __restrict__ slot_map,
    ushort* __restrict__ Vt, float* __restrict__ cacheOut)
{
    __shared__ ushort vs[64][130];                 // +2 pad: 2-way banks (free)
    const int tb  = blockIdx.x;
    const int kvh = blockIdx.y;
    const int b   = blockIdx.z;
    const int wv  = threadIdx.x >> 6;              // 0..3
    const int c   = threadIdx.x & 63;
    const int t0  = b * Ss + tb * 64;

    #pragma unroll
    for (int it = 0; it < 16; it++) {
        const int tr = wv + 4 * it;                // one 128-d row per wave
        const int t  = t0 + tr;
        ushort2 u = *(const ushort2*)&raw[(size_t)t * QKVO + (NHq + NKVh + kvh) * 128 + c * 2];
        *(ushort2*)&vs[tr][c * 2] = u;
        const int slot = slot_map[t];
        float2 f;
        f.x = bf2f(u.x);
        f.y = bf2f(u.y);
        *(float2*)&cacheOut[(size_t)NBLK * BSZ * NKVh * Dh +
                            (size_t)slot * (NKVh * Dh) + kvh * Dh + c * 2] = f;
    }
    __syncthreads();
    const int stok0 = tb * 64;
    #pragma unroll
    for (int it = 0; it < 32; it++) {
        const int d = wv * 32 + it;
        Vt[((size_t)(b * NKVh + kvh) * Dh + d) * Ss + stok0 + c] = vs[c][d];
    }
}

// ---------------- O-proj GEMM: C[M,N] = A[M,K] @ Bw[N,K]^T ----------------
// Tile 128x224, 4 waves (2M x 2N), wave 64x112, acc[4][7].
// Grid (3584/224=16, 4096/128=32) = 512 blocks.  LDS 67.6 KB (3 buf).
__global__ __launch_bounds__(256, 2) void gemm_bt(
    const ushort* __restrict__ A, const ushort* __restrict__ Bw,
    float* __restrict__ C, int N, int K)
{
    __shared__ ushort As[3][128 * 32];
    __shared__ ushort Bs[3][224 * 32];
    const int tid  = threadIdx.x;
    const int wv   = tid >> 6;
    const int lane = tid & 63;
    const int quad = lane >> 4;
    const int l16  = lane & 15;
    const int m0 = blockIdx.y * 128;
    const int n0 = blockIdx.x * 224;
    const int wm = (wv >> 1) * 64;
    const int wn = (wv & 1) * 112;

    f4v zero = {0.f, 0.f, 0.f, 0.f};
    f4v acc[4][7];
    #pragma unroll
    for (int i = 0; i < 4; i++)
        #pragma unroll
        for (int j = 0; j < 7; j++) acc[i][j] = zero;

    const int swz = ((lane & 3) ^ ((lane >> 3) & 3)) * 8;
    const int rS  = lane >> 2;
    const ushort* gA = A  + (size_t)(m0 + rS) * K + swz;
    const ushort* gB = Bw + (size_t)(n0 + rS) * K + swz;
    const int fsw = ((l16 >> 1) & 3) * 8;

    // A slots wv,wv+4 (2); B slots wv+4i<14 (waves 0,1: 4; 2,3: 3) -> 6,6,5,5
    #define BT_STAGE(buf, kt)                                                   \
        {                                                                       \
            _Pragma("unroll")                                                   \
            for (int i_ = 0; i_ < 2; i_++) {                                    \
                const int sl = wv + 4 * i_;                                     \
                async_cp16(&As[buf][sl * 16 * 32], gA + (size_t)(sl * 16) * K + (kt)); \
            }                                                                   \
            _Pragma("unroll")                                                   \
            for (int i_ = 0; i_ < 4; i_++) {                                    \
                const int sl = wv + 4 * i_;                                     \
                if (sl < 14)                                                    \
                    async_cp16(&Bs[buf][sl * 16 * 32], gB + (size_t)(sl * 16) * K + (kt)); \
            }                                                                   \
        }

    BT_STAGE(0, 0)
    BT_STAGE(1, 32)
    if (wv < 2) asm volatile("s_waitcnt vmcnt(6)" ::: "memory");
    else        asm volatile("s_waitcnt vmcnt(5)" ::: "memory");
    __builtin_amdgcn_s_barrier();
    __builtin_amdgcn_sched_barrier(0);

    const int NT = K / 32;
    for (int t = 0; t < NT; t++) {
        const ushort* Ac = As[t % 3];
        const ushort* Bc = Bs[t % 3];
        const int nb = (t + 2) % 3;
        const bool pf = (t + 2 < NT);

        s8v af[4], bfr[7];
        // ---- read group 1: af0-3, bfr0-3 (8 ds_reads) ----
        #pragma unroll
        for (int i = 0; i < 4; i++)
            af[i] = *(const s8v*)&Ac[(wm + i * 16 + l16) * 32 + ((quad * 8) ^ fsw)];
        #pragma unroll
        for (int j = 0; j < 4; j++)
            bfr[j] = *(const s8v*)&Bc[(wn + j * 16 + l16) * 32 + ((quad * 8) ^ fsw)];
        __builtin_amdgcn_sched_barrier(0);
        if (pf) BT_STAGE(nb, (t + 2) * 32)
        // ---- read group 2: bfr4-6 (3 ds_reads) ----
        #pragma unroll
        for (int j = 4; j < 7; j++)
            bfr[j] = *(const s8v*)&Bc[(wn + j * 16 + l16) * 32 + ((quad * 8) ^ fsw)];
        asm volatile("s_waitcnt lgkmcnt(3)" ::: "memory");   // g1 landed (11-8=3)
        __builtin_amdgcn_sched_barrier(0);
        __builtin_amdgcn_s_setprio(1);
        #pragma unroll
        for (int i = 0; i < 4; i++)             // MFMA g1 (16) || g2 drains
            #pragma unroll
            for (int j = 0; j < 4; j++)
                acc[i][j] = mfma16(af[i], bfr[j], acc[i][j]);
        asm volatile("s_waitcnt lgkmcnt(0)" ::: "memory");
        __builtin_amdgcn_sched_barrier(0);
        #pragma unroll
        for (int i = 0; i < 4; i++)             // MFMA g2 (12)
            #pragma unroll
            for (int j = 4; j < 7; j++)
                acc[i][j] = mfma16(af[i], bfr[j], acc[i][j]);
        __builtin_amdgcn_s_setprio(0);
        __builtin_amdgcn_sched_barrier(0);
        if (pf) {
            if (wv < 2) asm volatile("s_waitcnt vmcnt(6)" ::: "memory");
            else        asm volatile("s_waitcnt vmcnt(5)" ::: "memory");
        } else {
            asm volatile("s_waitcnt vmcnt(0)" ::: "memory");
        }
        __builtin_amdgcn_s_barrier();
        __builtin_amdgcn_sched_barrier(0);
    }
    #undef BT_STAGE

    #pragma unroll
    for (int i = 0; i < 4; i++) {
        const int m = m0 + wm + i * 16 + quad * 4;
        #pragma unroll
        for (int j = 0; j < 7; j++) {
            const int n = n0 + wn + j * 16 + l16;
            float* cp = C + (size_t)m * N + n;
            #pragma unroll
            for (int r = 0; r < 4; r++)
                cp[(size_t)r * N] = acc[i][j][r];
        }
    }
}

// ---------------- flash attention, S^T formulation (unchanged) ----------------
__global__ __launch_bounds__(256, 2) void attn(
    const ushort* __restrict__ Qb, const ushort* __restrict__ Kb,
    const ushort* __restrict__ Vt, ushort* __restrict__ ctx)
{
    __shared__ ushort Ksm[128 * 128];
    __shared__ ushort Vsm[128 * 128];

    const int tid  = threadIdx.x;
    const int w    = tid >> 6;
    const int lane = tid & 63;
    const int quad = lane >> 4;
    const int l16  = lane & 15;
    const int qt = (Ss / 128 - 1) - blockIdx.x;   // heavy blocks first
    const int h  = blockIdx.y;
    const int b  = blockIdx.z;
    const int kv = h / GRP;
    const int t0 = b * Ss + qt * 128;

    s8v qf[2][4];
    #pragma unroll
    for (int nt = 0; nt < 2; nt++)
        #pragma unroll
        for (int kd = 0; kd < 4; kd++)
            qf[nt][kd] = *(const s8v*)&Qb[((size_t)(t0 + w * 32 + nt * 16 + l16) * NHq + h) * Dh
                                          + kd * 32 + quad * 8];

    f4v zero = {0.f, 0.f, 0.f, 0.f};
    f4v o[2][8];
    #pragma unroll
    for (int nt = 0; nt < 2; nt++)
        #pragma unroll
        for (int dt = 0; dt < 8; dt++) o[nt][dt] = zero;
    float mstat[2] = {-1e30f, -1e30f};
    float dstat[2] = {0.f, 0.f};

    const int srow = lane >> 4;
    const int gch  = (lane & 15) ^ (w * 4 + srow);
    const ushort* gK = Kb + (size_t)(b * Ss) * (NKVh * Dh) + kv * Dh + gch * 8;
    const ushort* gV = Vt + (size_t)(b * NKVh + kv) * Dh * Ss + gch * 8;

    const int srcq0 = ((quad & 1) << 1) | (quad >> 1);
    const int addr0 = (srcq0 * 16 + l16) * 4;
    const int addr1 = ((srcq0 ^ 1) * 16 + l16) * 4;
    const bool oddq = (quad & 1);
    const bool lowq = (quad < 2);

    for (int kt = 0; kt <= qt; kt++) {
        const bool diag = (kt == qt);

        #pragma unroll
        for (int j = 0; j < 8; j++) {
            const int row = j * 16 + w * 4 + srow;
            async_cp16(&Ksm[(j * 16 + w * 4) * 128],
                       gK + (size_t)(kt * 128 + row) * (NKVh * Dh));
            async_cp16(&Vsm[(j * 16 + w * 4) * 128],
                       gV + (size_t)row * Ss + kt * 128);
        }
        __syncthreads();

        const int smax = diag ? (2 * w + 1) : 7;
        f4v sc[8][2];
        #pragma unroll
        for (int st = 0; st < 8; st++) { sc[st][0] = zero; sc[st][1] = zero; }
        #pragma unroll
        for (int st = 0; st < 8; st++) {
            if (st > smax) continue;
            #pragma unroll
            for (int kd = 0; kd < 4; kd++) {
                s8v kf = *(const s8v*)&Ksm[((st * 16 + l16) * 16 + ((kd * 4 + quad) ^ l16)) * 8];
                sc[st][0] = mfma16(kf, qf[0][kd], sc[st][0]);
                sc[st][1] = mfma16(kf, qf[1][kd], sc[st][1]);
            }
        }

        float alpha[2];
        #pragma unroll
        for (int nt = 0; nt < 2; nt++) {
            const int qcol = w * 32 + nt * 16 + l16;
            float rowm = -1e30f;
            #pragma unroll
            for (int st = 0; st < 8; st++) {
                if (st > smax) continue;
                #pragma unroll
                for (int r = 0; r < 4; r++) {
                    float v = sc[st][nt][r] * ATTN_SCALE;
                    if (diag && (st * 16 + quad * 4 + r > qcol)) v = -1e30f;
                    sc[st][nt][r] = v;
                    rowm = fmaxf(rowm, v);
                }
            }
            rowm = fmaxf(rowm, __shfl_xor(rowm, 16, 64));
            rowm = fmaxf(rowm, __shfl_xor(rowm, 32, 64));
            const float mn = fmaxf(mstat[nt], rowm);
            const float al = __expf(mstat[nt] - mn);
            float rs = 0.f;
            #pragma unroll
            for (int st = 0; st < 8; st++) {
                if (st > smax) continue;
                #pragma unroll
                for (int r = 0; r < 4; r++) {
                    const float p = __expf(sc[st][nt][r] - mn);
                    sc[st][nt][r] = p;
                    rs += p;
                }
            }
            rs += __shfl_xor(rs, 16, 64);
            rs += __shfl_xor(rs, 32, 64);
            dstat[nt] = dstat[nt] * al + rs;
            mstat[nt] = mn;
            alpha[nt] = al;
            #pragma unroll
            for (int dt = 0; dt < 8; dt++)
                #pragma unroll
                for (int r = 0; r < 4; r++) o[nt][dt][r] *= al;
        }

        const int spmax = diag ? w : 3;
        #pragma unroll
        for (int sp = 0; sp < 4; sp++) {
            if (sp > spmax) continue;
            s8v pf[2];
            #pragma unroll
            for (int nt = 0; nt < 2; nt++) {
                const uint32_t a01 = pkbf(sc[2 * sp][nt][0],     sc[2 * sp][nt][1]);
                const uint32_t a23 = pkbf(sc[2 * sp][nt][2],     sc[2 * sp][nt][3]);
                const uint32_t b01 = pkbf(sc[2 * sp + 1][nt][0], sc[2 * sp + 1][nt][1]);
                const uint32_t b23 = pkbf(sc[2 * sp + 1][nt][2], sc[2 * sp + 1][nt][3]);
                const int r0 = __builtin_amdgcn_ds_bpermute(addr0, (int)(oddq ? b01 : a01));
                const int r1 = __builtin_amdgcn_ds_bpermute(addr1, (int)(oddq ? a01 : b01));
                const int r2 = __builtin_amdgcn_ds_bpermute(addr0, (int)(oddq ? b23 : a23));
                const int r3 = __builtin_amdgcn_ds_bpermute(addr1, (int)(oddq ? a23 : b23));
                union { int d[4]; s8v v; } u;
                u.d[0] = lowq ? r0 : r1;
                u.d[1] = lowq ? r2 : r3;
                u.d[2] = lowq ? r1 : r0;
                u.d[3] = lowq ? r3 : r2;
                pf[nt] = u.v;
            }
            #pragma unroll
            for (int dt = 0; dt < 8; dt++) {
                s8v vf = *(const s8v*)&Vsm[((dt * 16 + l16) * 16 + ((sp * 4 + quad) ^ l16)) * 8];
                o[0][dt] = mfma16(vf, pf[0], o[0][dt]);
                o[1][dt] = mfma16(vf, pf[1], o[1][dt]);
            }
        }
        __syncthreads();
    }

    #pragma unroll
    for (int nt = 0; nt < 2; nt++) {
        const float inv = 1.0f / dstat[nt];
        const int trow = t0 + w * 32 + nt * 16 + l16;
        #pragma unroll
        for (int dt = 0; dt < 8; dt++) {
            ushort4 u;
            u.x = bf16r(o[nt][dt][0] * inv);
            u.y = bf16r(o[nt][dt][1] * inv);
            u.z = bf16r(o[nt][dt][2] * inv);
            u.w = bf16r(o[nt][dt][3] * inv);
            *(ushort4*)&ctx[(size_t)trow * Hd + h * Dh + dt * 16 + quad * 4] = u;
        }
    }
}

// ---------------- launch ----------------
extern "C" void kernel_launch(void* const* d_in, const int* in_sizes, int n_in,
                              void* d_out, int out_size, void* d_ws, size_t ws_size,
                              hipStream_t stream)
{
    const int*   positions = (const int*)d_in[0];
    const float* hidden    = (const float*)d_in[1];
    const float* kvc       = (const float*)d_in[2];
    const int*   slot_map  = (const int*)d_in[4];
    const float* w_qkv     = (const float*)d_in[7];
    const float* b_qkv     = (const float*)d_in[8];
    const float* w_o       = (const float*)d_in[9];

    float* out      = (float*)d_out;                 // (T, H) fp32
    float* cacheOut = out + (size_t)Tt * Hd;         // (2,NB,BS,NKV,D) fp32

    char* ws = (char*)d_ws;
    ushort* Xb    = (ushort*)(ws);                   // T*H bf16          29360128
    ushort* Wqkvb = (ushort*)(ws + 29360128);        // 4608*3584 bf16    33030144
    ushort* Wob   = (ushort*)(ws + 29360128);        // ALIAS: Wqkvb dead after gemm_qkv
    ushort* raw   = (ushort*)(ws + 62390272);        // T*4608 bf16       37748736
    ushort* Qb    = (ushort*)(ws + 100139008);       // T*NH*D bf16       29360128
    ushort* Kb    = (ushort*)(ws + 129499136);       // T*NKV*D bf16       4194304
    ushort* Vt    = (ushort*)(ws + 133693440);       // B*NKV*D*S bf16     4194304
    ushort* ctx   = Xb;                              // alias: Xb dead after gemm_qkv

    prep<<<dim3((PREP_N1 + PREP_N2 + PREP_N3 + 255) / 256), 256, 0, stream>>>(
        hidden, w_qkv, kvc, Xb, Wqkvb, cacheOut);
    gemm_qkv<<<dim3(QKVO / 288, Tt / 128), 256, 0, stream>>>(
        Xb, Wqkvb, b_qkv, raw);
    cvt_bf16<<<dim3(12544), 256, 0, stream>>>(w_o, Wob, 3211264);   // after gemm_qkv (alias)
    rope_qk<<<dim3(Tt * 32 / 4), 256, 0, stream>>>(
        raw, positions, slot_map, Qb, Kb, cacheOut);
    v_scatter<<<dim3(16, NKVh, Bb), 256, 0, stream>>>(
        raw, slot_map, Vt, cacheOut);
    attn<<<dim3(Ss / 128, NHq, Bb), 256, 0, stream>>>(Qb, Kb, Vt, ctx);
    gemm_bt<<<dim3(Hd / 224, Tt / 128), 256, 0, stream>>>(
        ctx, Wob, out, Hd, Hd);
}